// Round 3
// baseline (4579.670 us; speedup 1.0000x reference)
//
#include <hip/hip_runtime.h>
#include <cstdint>

// SplineConv MeshEncoder: 3 layers, K=3 DIM=3 M=27, dims 3->64->64->64.
// R16: edge-streaming Phase A with LDS-atomic scatter.
//   R14 (bytes) and R15 (VGPR cap) both NULL -> layer64 is serialization-
//   bound: per-wave per-edge chain (scalar meta load -> switch -> 8 FMAs
//   into the SAME 27 acc regs) gives ~176 cy/edge/CU with ~4 reqs in
//   flight per CU. Fix: all 8 waves stream the block's contiguous edge
//   range; accumulate w_c*xj into f32 LDS accf[node][27*64] via
//   atomicAdd (ds_add_f32: no register RMW chain, no switch -- corner
//   offsets are ds-immediates). Phase B reads f32 from LDS, converts to
//   bf16 in-reg, same MFMA + wb swizzle as before. Root row staged bf16
//   in padded LDS. h_a/h_b stay bf16 (R14, kept).

typedef __attribute__((ext_vector_type(8))) short short8;
typedef __attribute__((ext_vector_type(4))) float floatx4;

__device__ inline short f2bf(float f) {
    union { float f; unsigned u; } x; x.f = f;
    unsigned r = x.u + 0x7FFF + ((x.u >> 16) & 1);   // round-to-nearest-even
    return (short)(r >> 16);
}

__device__ inline float bf2f(unsigned short u) {
    union { unsigned u; float f; } x;
    x.u = ((unsigned)u) << 16;
    return x.f;
}

// ---------------- preprocessing (R10-proven) ----------------

__global__ void count_kernel(const int* __restrict__ ei, int* __restrict__ count, int E) {
    int e = blockIdx.x * blockDim.x + threadIdx.x;
    if (e < E) atomicAdd(&count[ei[E + e]], 1);
}

__global__ __launch_bounds__(1024) void scan_tile_kernel(const int* __restrict__ count,
                                                         int* __restrict__ row_ptr,
                                                         int* __restrict__ bsum, int N) {
    __shared__ int wsum[16];
    int tid = threadIdx.x, lane = tid & 63, wid = tid >> 6;
    int i = blockIdx.x * 1024 + tid;
    int v = (i < N) ? count[i] : 0;
    int incl = v;
#pragma unroll
    for (int off = 1; off < 64; off <<= 1) {
        int t = __shfl_up(incl, off, 64);
        if (lane >= off) incl += t;
    }
    if (lane == 63) wsum[wid] = incl;
    __syncthreads();
    if (tid < 16) {
        int w = wsum[tid];
#pragma unroll
        for (int off = 1; off < 16; off <<= 1) {
            int t = __shfl_up(w, off, 16);
            if ((tid & 15) >= off) w += t;
        }
        wsum[tid] = w;
    }
    __syncthreads();
    int waveoff = (wid > 0) ? wsum[wid - 1] : 0;
    if (i < N) row_ptr[i] = waveoff + incl - v;
    if (tid == 1023) bsum[blockIdx.x] = waveoff + incl;
}

__global__ __launch_bounds__(64) void scan_bsum_kernel(const int* __restrict__ bsum,
                                                       int* __restrict__ boff,
                                                       int* __restrict__ tot, int nb) {
    int tid = threadIdx.x;
    int v = (tid < nb) ? bsum[tid] : 0;
    int incl = v;
#pragma unroll
    for (int off = 1; off < 64; off <<= 1) {
        int t = __shfl_up(incl, off, 64);
        if (tid >= off) incl += t;
    }
    boff[tid] = incl - v;
    if (tid == 63) tot[0] = incl;
}

__global__ __launch_bounds__(1024) void scan_add_kernel(int* __restrict__ row_ptr,
                                                        const int* __restrict__ boff,
                                                        const int* __restrict__ tot,
                                                        int* __restrict__ cursor, int N) {
    int i = blockIdx.x * 1024 + threadIdx.x;
    if (i < N) {
        int r = row_ptr[i] + boff[blockIdx.x];
        row_ptr[i] = r;
        cursor[i] = r;
    }
    if (i == 0) row_ptr[N] = tot[0];
}

// Per edge: meta = src | base<<24, weights pre-scaled by 1/deg, scattered to
// dst-sorted position (two float4 stores). kidx = base + {0,1,3,4,9,10,12,13}[c].
__global__ void basis_sort_kernel(const int* __restrict__ ei, const float* __restrict__ attr,
                                  const int* __restrict__ count, int* __restrict__ cursor,
                                  int* __restrict__ s_meta, float* __restrict__ s_w, int E) {
    int e = blockIdx.x * blockDim.x + threadIdx.x;
    if (e >= E) return;
    int src = ei[e];
    int dst = ei[E + e];
    float f[3]; int i0[3];
#pragma unroll
    for (int d = 0; d < 3; d++) {
        float pos = attr[e * 3 + d] * 2.0f;          // K-1 = 2
        float fl = floorf(pos);
        fl = fminf(fmaxf(fl, 0.0f), 1.0f);           // clip to [0, K-2]
        i0[d] = (int)fl;
        f[d] = pos - fl;
    }
    int base = i0[0] + 3 * i0[1] + 9 * i0[2];        // in {0,1,3,4,9,10,12,13}
    float invd = 1.0f / fmaxf((float)count[dst], 1.0f);
    int p = atomicAdd(&cursor[dst], 1);
    s_meta[p] = src | (base << 24);
    float w[8];
#pragma unroll
    for (int c = 0; c < 8; c++) {
        float ww = 1.0f;
#pragma unroll
        for (int d = 0; d < 3; d++) {
            int off = (c >> d) & 1;
            ww *= off ? f[d] : (1.0f - f[d]);
        }
        w[c] = ww * invd;
    }
    floatx4 w03 = {w[0], w[1], w[2], w[3]};
    floatx4 w47 = {w[4], w[5], w[6], w[7]};
    *(floatx4*)(s_w + (size_t)p * 8) = w03;
    *(floatx4*)(s_w + (size_t)p * 8 + 4) = w47;
}

// Pre-swizzle [W(1728,64); Wr(64,64)] into bf16 MFMA B-frag order (R1-proven).
__global__ void build_wb2(const float* __restrict__ Wa, const float* __restrict__ Ra,
                          unsigned short* __restrict__ wba,
                          const float* __restrict__ Wb, const float* __restrict__ Rb,
                          unsigned short* __restrict__ wbb) {
    int idx0 = blockIdx.x * blockDim.x + threadIdx.x;   // [0, 2*4*56*64)
    int half = idx0 / (4 * 56 * 64);
    if (half >= 2) return;
    int idx = idx0 - half * (4 * 56 * 64);
    const float* W = half ? Wb : Wa;
    const float* Wr = half ? Rb : Ra;
    unsigned short* wb = half ? wbb : wba;
    int l = idx & 63;
    int c = (idx >> 6) % 56;
    int t = idx / (56 * 64);
    int q = l >> 4, o = t * 16 + (l & 15);
    short8 out;
#pragma unroll
    for (int j = 0; j < 8; j++) {
        int k = c * 32 + q * 8 + j;
        float v = (k < 1728) ? W[(size_t)k * 64 + o] : Wr[(size_t)(k - 1728) * 64 + o];
        out[j] = f2bf(v);
    }
    *(short8*)(wb + (size_t)idx * 8) = out;
}

// ---------------- layer 0 (CIN=3): dual-edge Phase A (unchanged) ----------------
__global__ __launch_bounds__(256) void layer0_kernel(
    const float* __restrict__ x, const float* __restrict__ W0,
    const float* __restrict__ Wr, const float* __restrict__ bias,
    const int* __restrict__ row_ptr, const int* __restrict__ s_meta,
    const float* __restrict__ s_w, unsigned short* __restrict__ h_out, int N) {
    constexpr int NPB = 32, KT = 84;
    __shared__ __align__(16) float acc[NPB * 2 * KT];   // 21.5 KB (dual copies)
    int tid = threadIdx.x, lane = tid & 63, wv = tid >> 6;
    int n0 = blockIdx.x * NPB;
    for (int k = tid; k < NPB * 2 * KT; k += 256) acc[k] = 0.0f;
    __syncthreads();

    int d = lane >> 5, hl = lane & 31;
    int c = hl / 3, i = hl - c * 3;
    bool act = (hl < 24);
    int cc = act ? c : 0;
    int coff = (c & 1) + 3 * ((c >> 1) & 1) + 9 * (c >> 2);   // corner offset

    for (int g2 = 0; g2 < 8; g2++) {
        int g = wv * 8 + g2;
        int n = n0 + g;
        if (n >= N) continue;
        if (lane < 3) acc[(g * 2) * KT + 81 + lane] = x[(size_t)n * 3 + lane];  // root
        int rs = row_ptr[n], re = row_ptr[n + 1];
        int npairs = (re - rs + 1) >> 1;
        float* accd = &acc[(g * 2 + d) * KT];
        for (int pb = 0; pb < npairs; pb += 4) {
            int metas[4]; float ws_[4], xs_[4];
#pragma unroll
            for (int j = 0; j < 4; j++) {            // clamp invalid -> rs (valid, w=0)
                int ej = rs + (pb + j) * 2 + d;
                bool v = (pb + j < npairs) && (ej < re);
                int ec = v ? ej : rs;
                metas[j] = s_meta[ec];
                float wv_ = s_w[(size_t)ec * 8 + cc];
                ws_[j] = v ? wv_ : 0.0f;
            }
#pragma unroll
            for (int j = 0; j < 4; j++)
                xs_[j] = x[(size_t)(metas[j] & 0xFFFFFF) * 3 + i];
#pragma unroll
            for (int j = 0; j < 4; j++) {
                int kidx = ((metas[j] >> 24) & 0xF) + coff;
                if (act) accd[kidx * 3 + i] += ws_[j] * xs_[j];
            }
        }
    }
    __syncthreads();

    // Phase B: o = lane, W in 84 registers; sum the dual acc copies.
    int o = lane;
    float wreg[KT];
#pragma unroll
    for (int k = 0; k < KT; k++)
        wreg[k] = (k < 81) ? W0[k * 64 + o] : Wr[(k - 81) * 64 + o];
    float bv = bias[o];
    for (int g = wv; g < NPB; g += 4) {
        int n = n0 + g;
        if (n >= N) break;
        float s = bv;
#pragma unroll
        for (int k4 = 0; k4 < KT; k4 += 4) {
            floatx4 a0 = *(const floatx4*)&acc[(g * 2) * KT + k4];
            floatx4 a1 = *(const floatx4*)&acc[(g * 2 + 1) * KT + k4];
            s += (a0.x + a1.x) * wreg[k4] + (a0.y + a1.y) * wreg[k4 + 1]
               + (a0.z + a1.z) * wreg[k4 + 2] + (a0.w + a1.w) * wreg[k4 + 3];
        }
        h_out[(size_t)n * 64 + o] = (unsigned short)f2bf(fmaxf(s, 0.0f));
    }
}

// ---------------- 64-ch layers: edge-streaming + LDS-atomic Phase A ----------------
// accf[node][k], k = m*64 + ch_in, stride AST = 27*64+4 (bank spread: row
// base banks r*4). Root row kept bf16 in rootb[node][72] (stride 72 for
// bank spread). Phase B: same MFMA/wb/epilogue as R12, A-frags converted
// f32->bf16 in-reg; chunks 54,55 come from rootb.
template <bool OUTF32>
__global__ __launch_bounds__(512, 4) void layer64_kernel(
    const unsigned short* __restrict__ h_in, const unsigned short* __restrict__ wb,
    const float* __restrict__ bias, const int* __restrict__ row_ptr,
    const int* __restrict__ s_meta, const float* __restrict__ s_w,
    void* __restrict__ h_out, int N) {
    constexpr int NPB = 8;
    constexpr int AST = 27 * 64 + 4;                     // 1732 f32
    __shared__ __align__(16) float accf[NPB * AST];      // 55,424 B
    __shared__ __align__(16) unsigned short rootb[NPB * 72];  // 1,152 B
    int tid = threadIdx.x, lane = tid & 63;
    int wvu = __builtin_amdgcn_readfirstlane(tid >> 6);  // uniform wave id 0..7
    int n0 = blockIdx.x * NPB;

    // zero accumulator + stage root rows (bf16)
    for (int k = tid * 4; k < NPB * AST; k += 512 * 4)
        *(floatx4*)&accf[k] = (floatx4){0.0f, 0.0f, 0.0f, 0.0f};
    {
        int n = n0 + wvu;
        rootb[wvu * 72 + lane] = (n < N) ? h_in[(size_t)n * 64 + lane] : (unsigned short)0;
    }
    __syncthreads();

    // ---- Phase A: 8 waves cooperatively stream the block's edge range ----
    {
        int rs0 = row_ptr[n0 < N ? n0 : N];
        int b1 = row_ptr[n0 + 1 < N ? n0 + 1 : N];
        int b2 = row_ptr[n0 + 2 < N ? n0 + 2 : N];
        int b3 = row_ptr[n0 + 3 < N ? n0 + 3 : N];
        int b4 = row_ptr[n0 + 4 < N ? n0 + 4 : N];
        int b5 = row_ptr[n0 + 5 < N ? n0 + 5 : N];
        int b6 = row_ptr[n0 + 6 < N ? n0 + 6 : N];
        int b7 = row_ptr[n0 + 7 < N ? n0 + 7 : N];
        int re0 = row_ptr[n0 + 8 < N ? n0 + 8 : N];
        int len = re0 - rs0;
        int we0 = rs0 + (len * wvu) / 8;
        int we1 = rs0 + (len * (wvu + 1)) / 8;
        int e = we0;

#define EDGEA_BODY(J) do { \
    int ee = e + (J); \
    int no = (ee >= b1) + (ee >= b2) + (ee >= b3) + (ee >= b4) \
           + (ee >= b5) + (ee >= b6) + (ee >= b7); \
    float* ap = accf + no * AST + (((metas[J] >> 24) & 0xF) * 64) + lane; \
    float xx = xjv[J]; \
    atomicAdd(&ap[0],       wAv[J].x * xx); \
    atomicAdd(&ap[64],      wAv[J].y * xx); \
    atomicAdd(&ap[3 * 64],  wAv[J].z * xx); \
    atomicAdd(&ap[4 * 64],  wAv[J].w * xx); \
    atomicAdd(&ap[9 * 64],  wBv[J].x * xx); \
    atomicAdd(&ap[10 * 64], wBv[J].y * xx); \
    atomicAdd(&ap[12 * 64], wBv[J].z * xx); \
    atomicAdd(&ap[13 * 64], wBv[J].w * xx); \
} while (0)

#define EDGEA_BATCH(SZ) do { \
    int metas[SZ]; float xjv[SZ]; floatx4 wAv[SZ], wBv[SZ]; \
    _Pragma("unroll") for (int j = 0; j < SZ; j++) { \
        metas[j] = s_meta[e + j]; \
        wAv[j] = *(const floatx4*)(s_w + (size_t)(e + j) * 8); \
        wBv[j] = *(const floatx4*)(s_w + (size_t)(e + j) * 8 + 4); \
    } \
    _Pragma("unroll") for (int j = 0; j < SZ; j++) \
        xjv[j] = bf2f(h_in[(size_t)(metas[j] & 0xFFFFFF) * 64 + lane]); \
    _Pragma("unroll") for (int j = 0; j < SZ; j++) EDGEA_BODY(j); \
    e += SZ; \
} while (0)

        while (e + 8 <= we1) EDGEA_BATCH(8);
        if (e + 4 <= we1) EDGEA_BATCH(4);
        while (e < we1) EDGEA_BATCH(1);
#undef EDGEA_BATCH
#undef EDGEA_BODY
    }
    __syncthreads();

    // ---- Phase B: 2-way split-K MFMA, A-frags f32->bf16 in-reg ----
    {
        int t = wvu & 3;
        int hf = wvu >> 2;
        const float* apf = accf + (lane & 7) * AST + ((lane >> 4) * 8);
        const unsigned short* rp = rootb + (lane & 7) * 72 + ((lane >> 4) * 8);
        floatx4 facc = {0.0f, 0.0f, 0.0f, 0.0f};
        const unsigned short* wbp = wb + ((size_t)(t * 56) * 64 + lane) * 8;

#define PB_F32(C) do { \
    floatx4 lo = *(const floatx4*)(apf + (C) * 32); \
    floatx4 hi = *(const floatx4*)(apf + (C) * 32 + 4); \
    short8 af; \
    af[0] = f2bf(lo.x); af[1] = f2bf(lo.y); af[2] = f2bf(lo.z); af[3] = f2bf(lo.w); \
    af[4] = f2bf(hi.x); af[5] = f2bf(hi.y); af[6] = f2bf(hi.z); af[7] = f2bf(hi.w); \
    short8 bfr = *(const short8*)(wbp + (size_t)(C) * 64 * 8); \
    facc = __builtin_amdgcn_mfma_f32_16x16x32_bf16(af, bfr, facc, 0, 0, 0); \
} while (0)

        if (hf == 0) {
#pragma unroll
            for (int ci = 0; ci < 28; ci++) PB_F32(ci);
        } else {
#pragma unroll
            for (int ci = 0; ci < 26; ci++) PB_F32(28 + ci);
#pragma unroll
            for (int cr = 0; cr < 2; cr++) {
                int c = 54 + cr;
                short8 af = *(const short8*)(rp + cr * 32);
                short8 bfr = *(const short8*)(wbp + (size_t)c * 64 * 8);
                facc = __builtin_amdgcn_mfma_f32_16x16x32_bf16(af, bfr, facc, 0, 0, 0);
            }
        }
#undef PB_F32

        __syncthreads();               // all LDS reads for MFMA complete
        float* pf = accf;              // reuse: 8 waves x 256 floats = 8KB
#pragma unroll
        for (int r = 0; r < 4; r++) pf[wvu * 256 + r * 64 + lane] = facc[r];
        __syncthreads();
        if (wvu < 4) {
            int o = t * 16 + (lane & 15);
            float bv = bias[o];
#pragma unroll
            for (int r = 0; r < 4; r++) {
                int m = (lane >> 4) * 4 + r;
                if (m < 8) {
                    int n = n0 + m;
                    if (n < N) {
                        float s = pf[t * 256 + r * 64 + lane]
                                + pf[(t + 4) * 256 + r * 64 + lane];
                        float val = fmaxf(s + bv, 0.0f);
                        if (OUTF32) {
                            ((float*)h_out)[(size_t)n * 64 + o] = val;
                        } else {
                            ((unsigned short*)h_out)[(size_t)n * 64 + o] =
                                (unsigned short)f2bf(val);
                        }
                    }
                }
            }
        }
    }
}

extern "C" void kernel_launch(void* const* d_in, const int* in_sizes, int n_in,
                              void* d_out, int out_size, void* d_ws, size_t ws_size,
                              hipStream_t stream) {
    (void)n_in; (void)out_size; (void)ws_size;
    const float* x    = (const float*)d_in[0];
    const int*   ei   = (const int*)d_in[1];
    const float* attr = (const float*)d_in[2];
    const float* W0 = (const float*)d_in[3];
    const float* R0 = (const float*)d_in[4];
    const float* B0 = (const float*)d_in[5];
    const float* W1 = (const float*)d_in[6];
    const float* R1 = (const float*)d_in[7];
    const float* B1 = (const float*)d_in[8];
    const float* W2 = (const float*)d_in[9];
    const float* R2 = (const float*)d_in[10];
    const float* B2 = (const float*)d_in[11];
    const int N = in_sizes[0] / 3;
    const int E = in_sizes[1] / 2;

    char* ws = (char*)d_ws;
    size_t off = 0;
    auto alloc = [&](size_t bytes) {
        size_t cur = off;
        off = (off + bytes + 255) & ~(size_t)255;
        return cur;
    };
    int* row_ptr = (int*)(ws + alloc((size_t)(N + 1) * 4));
    int* count   = (int*)(ws + alloc((size_t)N * 4));
    int* cursor  = (int*)(ws + alloc((size_t)N * 4));
    int* bsum    = (int*)(ws + alloc(64 * 4));
    int* boff    = (int*)(ws + alloc(64 * 4));
    int* tot     = (int*)(ws + alloc(4));
    int* s_meta  = (int*)(ws + alloc((size_t)E * 4));
    float* s_w   = (float*)(ws + alloc((size_t)E * 8 * 4));
    unsigned short* h_a = (unsigned short*)(ws + alloc((size_t)N * 64 * 2));
    unsigned short* h_b = (unsigned short*)(ws + alloc((size_t)N * 64 * 2));
    unsigned short* wb1 = (unsigned short*)(ws + alloc((size_t)4 * 56 * 64 * 8 * 2));
    unsigned short* wb2 = (unsigned short*)(ws + alloc((size_t)4 * 56 * 64 * 8 * 2));

    int nb = (N + 1023) / 1024;   // 49 <= 64

    hipMemsetAsync(count, 0, (size_t)N * 4, stream);
    count_kernel<<<(E + 255) / 256, 256, 0, stream>>>(ei, count, E);
    scan_tile_kernel<<<nb, 1024, 0, stream>>>(count, row_ptr, bsum, N);
    scan_bsum_kernel<<<1, 64, 0, stream>>>(bsum, boff, tot, nb);
    scan_add_kernel<<<nb, 1024, 0, stream>>>(row_ptr, boff, tot, cursor, N);
    basis_sort_kernel<<<(E + 255) / 256, 256, 0, stream>>>(ei, attr, count, cursor,
                                                           s_meta, s_w, E);
    build_wb2<<<(2 * 4 * 56 * 64 + 255) / 256, 256, 0, stream>>>(W1, R1, wb1,
                                                                 W2, R2, wb2);

    layer0_kernel<<<(N + 31) / 32, 256, 0, stream>>>(x, W0, R0, B0, row_ptr,
                                                     s_meta, s_w, h_a, N);
    layer64_kernel<false><<<(N + 7) / 8, 512, 0, stream>>>(h_a, wb1, B1, row_ptr,
                                                           s_meta, s_w, h_b, N);
    layer64_kernel<true><<<(N + 7) / 8, 512, 0, stream>>>(h_b, wb2, B2, row_ptr,
                                                          s_meta, s_w, (float*)d_out, N);
}

// Round 4
// 728.825 us; speedup vs baseline: 6.2836x; 6.2836x over previous
//
#include <hip/hip_runtime.h>
#include <cstdint>

// SplineConv MeshEncoder: 3 layers, K=3 DIM=3 M=27, dims 3->64->64->64.
// R17 = R15 base (R16 LDS-atomic Phase A REVERTED: f32 LDS atomicAdd is a
// CAS-loop, 10x regression, 1.1e7 bank conflicts) + dual-wave-per-node
// Phase A in layer64:
//   Evidence: per-wave edge chain runs at ~2.4k cy/edge (~4 outstanding
//   reqs/CU); compiler pins VGPR=60 so the 16-gather batch never gets in
//   flight together (R15 cap-raise null). If the per-wave chain is
//   irreducible, double the number of chains: wave w -> node w>>1,
//   parity w&1 processes edges rs+p, rs+p+2, ... NPB 8->4, grid x2.
//   accb rows = node*2+parity (8 rows: LDS + Phase-B MFMA unchanged);
//   epilogue sums row pairs (MFMA M-slack absorbs the partial-sum).
//   Parity-1 rows write zeros in the root chunks so root counts once.

typedef __attribute__((ext_vector_type(8))) short short8;
typedef __attribute__((ext_vector_type(4))) float floatx4;

__device__ inline short f2bf(float f) {
    union { float f; unsigned u; } x; x.f = f;
    unsigned r = x.u + 0x7FFF + ((x.u >> 16) & 1);   // round-to-nearest-even
    return (short)(r >> 16);
}

__device__ inline float bf2f(unsigned short u) {
    union { unsigned u; float f; } x;
    x.u = ((unsigned)u) << 16;
    return x.f;
}

// ---------------- preprocessing (R10-proven) ----------------

__global__ void count_kernel(const int* __restrict__ ei, int* __restrict__ count, int E) {
    int e = blockIdx.x * blockDim.x + threadIdx.x;
    if (e < E) atomicAdd(&count[ei[E + e]], 1);
}

__global__ __launch_bounds__(1024) void scan_tile_kernel(const int* __restrict__ count,
                                                         int* __restrict__ row_ptr,
                                                         int* __restrict__ bsum, int N) {
    __shared__ int wsum[16];
    int tid = threadIdx.x, lane = tid & 63, wid = tid >> 6;
    int i = blockIdx.x * 1024 + tid;
    int v = (i < N) ? count[i] : 0;
    int incl = v;
#pragma unroll
    for (int off = 1; off < 64; off <<= 1) {
        int t = __shfl_up(incl, off, 64);
        if (lane >= off) incl += t;
    }
    if (lane == 63) wsum[wid] = incl;
    __syncthreads();
    if (tid < 16) {
        int w = wsum[tid];
#pragma unroll
        for (int off = 1; off < 16; off <<= 1) {
            int t = __shfl_up(w, off, 16);
            if ((tid & 15) >= off) w += t;
        }
        wsum[tid] = w;
    }
    __syncthreads();
    int waveoff = (wid > 0) ? wsum[wid - 1] : 0;
    if (i < N) row_ptr[i] = waveoff + incl - v;
    if (tid == 1023) bsum[blockIdx.x] = waveoff + incl;
}

__global__ __launch_bounds__(64) void scan_bsum_kernel(const int* __restrict__ bsum,
                                                       int* __restrict__ boff,
                                                       int* __restrict__ tot, int nb) {
    int tid = threadIdx.x;
    int v = (tid < nb) ? bsum[tid] : 0;
    int incl = v;
#pragma unroll
    for (int off = 1; off < 64; off <<= 1) {
        int t = __shfl_up(incl, off, 64);
        if (tid >= off) incl += t;
    }
    boff[tid] = incl - v;
    if (tid == 63) tot[0] = incl;
}

__global__ __launch_bounds__(1024) void scan_add_kernel(int* __restrict__ row_ptr,
                                                        const int* __restrict__ boff,
                                                        const int* __restrict__ tot,
                                                        int* __restrict__ cursor, int N) {
    int i = blockIdx.x * 1024 + threadIdx.x;
    if (i < N) {
        int r = row_ptr[i] + boff[blockIdx.x];
        row_ptr[i] = r;
        cursor[i] = r;
    }
    if (i == 0) row_ptr[N] = tot[0];
}

// Per edge: meta = src | base<<24, weights pre-scaled by 1/deg, scattered to
// dst-sorted position (two float4 stores). kidx = base + {0,1,3,4,9,10,12,13}[c].
__global__ void basis_sort_kernel(const int* __restrict__ ei, const float* __restrict__ attr,
                                  const int* __restrict__ count, int* __restrict__ cursor,
                                  int* __restrict__ s_meta, float* __restrict__ s_w, int E) {
    int e = blockIdx.x * blockDim.x + threadIdx.x;
    if (e >= E) return;
    int src = ei[e];
    int dst = ei[E + e];
    float f[3]; int i0[3];
#pragma unroll
    for (int d = 0; d < 3; d++) {
        float pos = attr[e * 3 + d] * 2.0f;          // K-1 = 2
        float fl = floorf(pos);
        fl = fminf(fmaxf(fl, 0.0f), 1.0f);           // clip to [0, K-2]
        i0[d] = (int)fl;
        f[d] = pos - fl;
    }
    int base = i0[0] + 3 * i0[1] + 9 * i0[2];        // in {0,1,3,4,9,10,12,13}
    float invd = 1.0f / fmaxf((float)count[dst], 1.0f);
    int p = atomicAdd(&cursor[dst], 1);
    s_meta[p] = src | (base << 24);
    float w[8];
#pragma unroll
    for (int c = 0; c < 8; c++) {
        float ww = 1.0f;
#pragma unroll
        for (int d = 0; d < 3; d++) {
            int off = (c >> d) & 1;
            ww *= off ? f[d] : (1.0f - f[d]);
        }
        w[c] = ww * invd;
    }
    floatx4 w03 = {w[0], w[1], w[2], w[3]};
    floatx4 w47 = {w[4], w[5], w[6], w[7]};
    *(floatx4*)(s_w + (size_t)p * 8) = w03;
    *(floatx4*)(s_w + (size_t)p * 8 + 4) = w47;
}

// Pre-swizzle [W(1728,64); Wr(64,64)] into bf16 MFMA B-frag order (R1-proven).
__global__ void build_wb2(const float* __restrict__ Wa, const float* __restrict__ Ra,
                          unsigned short* __restrict__ wba,
                          const float* __restrict__ Wb, const float* __restrict__ Rb,
                          unsigned short* __restrict__ wbb) {
    int idx0 = blockIdx.x * blockDim.x + threadIdx.x;   // [0, 2*4*56*64)
    int half = idx0 / (4 * 56 * 64);
    if (half >= 2) return;
    int idx = idx0 - half * (4 * 56 * 64);
    const float* W = half ? Wb : Wa;
    const float* Wr = half ? Rb : Ra;
    unsigned short* wb = half ? wbb : wba;
    int l = idx & 63;
    int c = (idx >> 6) % 56;
    int t = idx / (56 * 64);
    int q = l >> 4, o = t * 16 + (l & 15);
    short8 out;
#pragma unroll
    for (int j = 0; j < 8; j++) {
        int k = c * 32 + q * 8 + j;
        float v = (k < 1728) ? W[(size_t)k * 64 + o] : Wr[(size_t)(k - 1728) * 64 + o];
        out[j] = f2bf(v);
    }
    *(short8*)(wb + (size_t)idx * 8) = out;
}

// ---------------- layer 0 (CIN=3): dual-edge Phase A (unchanged) ----------------
__global__ __launch_bounds__(256) void layer0_kernel(
    const float* __restrict__ x, const float* __restrict__ W0,
    const float* __restrict__ Wr, const float* __restrict__ bias,
    const int* __restrict__ row_ptr, const int* __restrict__ s_meta,
    const float* __restrict__ s_w, unsigned short* __restrict__ h_out, int N) {
    constexpr int NPB = 32, KT = 84;
    __shared__ __align__(16) float acc[NPB * 2 * KT];   // 21.5 KB (dual copies)
    int tid = threadIdx.x, lane = tid & 63, wv = tid >> 6;
    int n0 = blockIdx.x * NPB;
    for (int k = tid; k < NPB * 2 * KT; k += 256) acc[k] = 0.0f;
    __syncthreads();

    int d = lane >> 5, hl = lane & 31;
    int c = hl / 3, i = hl - c * 3;
    bool act = (hl < 24);
    int cc = act ? c : 0;
    int coff = (c & 1) + 3 * ((c >> 1) & 1) + 9 * (c >> 2);   // corner offset

    for (int g2 = 0; g2 < 8; g2++) {
        int g = wv * 8 + g2;
        int n = n0 + g;
        if (n >= N) continue;
        if (lane < 3) acc[(g * 2) * KT + 81 + lane] = x[(size_t)n * 3 + lane];  // root
        int rs = row_ptr[n], re = row_ptr[n + 1];
        int npairs = (re - rs + 1) >> 1;
        float* accd = &acc[(g * 2 + d) * KT];
        for (int pb = 0; pb < npairs; pb += 4) {
            int metas[4]; float ws_[4], xs_[4];
#pragma unroll
            for (int j = 0; j < 4; j++) {            // clamp invalid -> rs (valid, w=0)
                int ej = rs + (pb + j) * 2 + d;
                bool v = (pb + j < npairs) && (ej < re);
                int ec = v ? ej : rs;
                metas[j] = s_meta[ec];
                float wv_ = s_w[(size_t)ec * 8 + cc];
                ws_[j] = v ? wv_ : 0.0f;
            }
#pragma unroll
            for (int j = 0; j < 4; j++)
                xs_[j] = x[(size_t)(metas[j] & 0xFFFFFF) * 3 + i];
#pragma unroll
            for (int j = 0; j < 4; j++) {
                int kidx = ((metas[j] >> 24) & 0xF) + coff;
                if (act) accd[kidx * 3 + i] += ws_[j] * xs_[j];
            }
        }
    }
    __syncthreads();

    // Phase B: o = lane, W in 84 registers; sum the dual acc copies.
    int o = lane;
    float wreg[KT];
#pragma unroll
    for (int k = 0; k < KT; k++)
        wreg[k] = (k < 81) ? W0[k * 64 + o] : Wr[(k - 81) * 64 + o];
    float bv = bias[o];
    for (int g = wv; g < NPB; g += 4) {
        int n = n0 + g;
        if (n >= N) break;
        float s = bv;
#pragma unroll
        for (int k4 = 0; k4 < KT; k4 += 4) {
            floatx4 a0 = *(const floatx4*)&acc[(g * 2) * KT + k4];
            floatx4 a1 = *(const floatx4*)&acc[(g * 2 + 1) * KT + k4];
            s += (a0.x + a1.x) * wreg[k4] + (a0.y + a1.y) * wreg[k4 + 1]
               + (a0.z + a1.z) * wreg[k4 + 2] + (a0.w + a1.w) * wreg[k4 + 3];
        }
        h_out[(size_t)n * 64 + o] = (unsigned short)f2bf(fmaxf(s, 0.0f));
    }
}

// ---------------- 64-ch layers: dual-wave-per-node Phase A ----------------
// Wave w -> node (w>>1), parity (w&1): processes edges rs+p, rs+p+2, ...
// accb row = node*2+parity (8 rows). Phase B MFMA identical to R12; the
// epilogue sums row pairs (2q, 2q+1) -> node q. Parity-1 rows zero the
// root chunks (k=1728..1791) so the root is counted once.
template <bool OUTF32>
__global__ __launch_bounds__(512) void layer64_kernel(
    const unsigned short* __restrict__ h_in, const unsigned short* __restrict__ wb,
    const float* __restrict__ bias, const int* __restrict__ row_ptr,
    const int* __restrict__ s_meta, const float* __restrict__ s_w,
    void* __restrict__ h_out, int N) {
    constexpr int NPB = 4;
    constexpr int STR = 1808;            // shorts; dword-stride 904 = even bank spread
    __shared__ __align__(16) unsigned short accb[8 * STR];   // 28,928 B
    int tid = threadIdx.x, lane = tid & 63;
    int wvu = __builtin_amdgcn_readfirstlane(tid >> 6);   // uniform wave id 0..7
    int n0 = blockIdx.x * NPB;

#define EDGE_FMA(EIDX, XJ) do { \
    const float* wp = s_w + (size_t)(EIDX) * 8; \
    float w0 = wp[0], w1 = wp[1], w2 = wp[2], w3 = wp[3]; \
    float w4 = wp[4], w5 = wp[5], w6 = wp[6], w7 = wp[7]; \
    float xj = (XJ); \
    switch (bases) { \
    case 0:  acc[0]+=w0*xj;  acc[1]+=w1*xj;  acc[3]+=w2*xj;  acc[4]+=w3*xj; \
             acc[9]+=w4*xj;  acc[10]+=w5*xj; acc[12]+=w6*xj; acc[13]+=w7*xj; break; \
    case 1:  acc[1]+=w0*xj;  acc[2]+=w1*xj;  acc[4]+=w2*xj;  acc[5]+=w3*xj; \
             acc[10]+=w4*xj; acc[11]+=w5*xj; acc[13]+=w6*xj; acc[14]+=w7*xj; break; \
    case 3:  acc[3]+=w0*xj;  acc[4]+=w1*xj;  acc[6]+=w2*xj;  acc[7]+=w3*xj; \
             acc[12]+=w4*xj; acc[13]+=w5*xj; acc[15]+=w6*xj; acc[16]+=w7*xj; break; \
    case 4:  acc[4]+=w0*xj;  acc[5]+=w1*xj;  acc[7]+=w2*xj;  acc[8]+=w3*xj; \
             acc[13]+=w4*xj; acc[14]+=w5*xj; acc[16]+=w6*xj; acc[17]+=w7*xj; break; \
    case 9:  acc[9]+=w0*xj;  acc[10]+=w1*xj; acc[12]+=w2*xj; acc[13]+=w3*xj; \
             acc[18]+=w4*xj; acc[19]+=w5*xj; acc[21]+=w6*xj; acc[22]+=w7*xj; break; \
    case 10: acc[10]+=w0*xj; acc[11]+=w1*xj; acc[13]+=w2*xj; acc[14]+=w3*xj; \
             acc[19]+=w4*xj; acc[20]+=w5*xj; acc[22]+=w6*xj; acc[23]+=w7*xj; break; \
    case 12: acc[12]+=w0*xj; acc[13]+=w1*xj; acc[15]+=w2*xj; acc[16]+=w3*xj; \
             acc[21]+=w4*xj; acc[22]+=w5*xj; acc[24]+=w6*xj; acc[25]+=w7*xj; break; \
    default: acc[13]+=w0*xj; acc[14]+=w1*xj; acc[16]+=w2*xj; acc[17]+=w3*xj; \
             acc[22]+=w4*xj; acc[23]+=w5*xj; acc[25]+=w6*xj; acc[26]+=w7*xj; break; } \
} while (0)

#define BATCH(SZ) do { \
    int metas[SZ]; float xjs[SZ]; \
    _Pragma("unroll") for (int j = 0; j < SZ; j++) metas[j] = s_meta[eb + 2 * j]; \
    _Pragma("unroll") for (int j = 0; j < SZ; j++) \
        xjs[j] = bf2f(h_in[(size_t)(metas[j] & 0xFFFFFF) * 64 + lane]); \
    _Pragma("unroll") for (int j = 0; j < SZ; j++) { \
        int bases = (metas[j] >> 24) & 0xF; \
        EDGE_FMA(eb + 2 * j, xjs[j]); \
    } \
    i += SZ; \
} while (0)

    // Phase A: wave wvu -> node (wvu>>1), parity (wvu&1).
    {
        int r = wvu;
        int n = n0 + (wvu >> 1);
        int p = wvu & 1;
        unsigned short* arowb = &accb[r * STR];
        if (n >= N) {   // tail hygiene: zero the row so MFMA sees no stale LDS
            for (int k = lane; k < 1792; k += 64) arowb[k] = 0;
        } else {
            float acc[27];
#pragma unroll
            for (int m = 0; m < 27; m++) acc[m] = 0.0f;
            int rs = row_ptr[n], re = row_ptr[n + 1];
            int cnt = (re - rs - p + 1) >> 1;   // #edges for this parity
            int i = 0;
            while (i + 16 <= cnt) { int eb = rs + p + 2 * i; BATCH(16); }
            if (i + 8 <= cnt) { int eb = rs + p + 2 * i; BATCH(8); }
            if (i + 4 <= cnt) { int eb = rs + p + 2 * i; BATCH(4); }
            for (; i < cnt; ) { int eb = rs + p + 2 * i; BATCH(1); }
#pragma unroll
            for (int m = 0; m < 27; m++)
                arowb[m * 64 + lane] = (unsigned short)f2bf(acc[m]);
            // root chunks: parity 0 carries the root row, parity 1 zeros.
            arowb[1728 + lane] = p ? (unsigned short)0 : h_in[(size_t)n * 64 + lane];
        }
    }
#undef BATCH
#undef EDGE_FMA
    __syncthreads();

    // Phase B: all 8 waves, 2-way split-K (broadcast A reads, conflict-free).
    {
        int t = wvu & 3;
        int hf = wvu >> 2;
        const unsigned short* ap = accb + (lane & 7) * STR + ((lane >> 4) * 8);
        floatx4 facc = {0.0f, 0.0f, 0.0f, 0.0f};
        const unsigned short* wbp = wb + ((size_t)(t * 56) * 64 + lane) * 8;
#pragma unroll
        for (int ci = 0; ci < 28; ci++) {
            int c = hf * 28 + ci;
            short8 af = *(const short8*)(ap + c * 32);
            short8 bfr = *(const short8*)(wbp + (size_t)c * 64 * 8);
            facc = __builtin_amdgcn_mfma_f32_16x16x32_bf16(af, bfr, facc, 0, 0, 0);
        }
        __syncthreads();               // all MFMA reads of accb complete
        float* pf = (float*)accb;      // 8 waves x 256 floats = 8KB (fits)
#pragma unroll
        for (int r = 0; r < 4; r++) pf[wvu * 256 + r * 64 + lane] = facc[r];
        __syncthreads();
        if (wvu < 4) {
            int o = t * 16 + (lane & 15);
            float bv = bias[o];
#pragma unroll
            for (int j = 0; j < 2; j++) {
                int q = (lane >> 4) * 2 + j;      // node within block (rows 2q,2q+1)
                if (q < 4) {
                    int n = n0 + q;
                    if (n < N) {
                        float s = pf[t * 256 + (2 * j) * 64 + lane]
                                + pf[t * 256 + (2 * j + 1) * 64 + lane]
                                + pf[(t + 4) * 256 + (2 * j) * 64 + lane]
                                + pf[(t + 4) * 256 + (2 * j + 1) * 64 + lane];
                        float val = fmaxf(s + bv, 0.0f);
                        if (OUTF32) {
                            ((float*)h_out)[(size_t)n * 64 + o] = val;
                        } else {
                            ((unsigned short*)h_out)[(size_t)n * 64 + o] =
                                (unsigned short)f2bf(val);
                        }
                    }
                }
            }
        }
    }
}

extern "C" void kernel_launch(void* const* d_in, const int* in_sizes, int n_in,
                              void* d_out, int out_size, void* d_ws, size_t ws_size,
                              hipStream_t stream) {
    (void)n_in; (void)out_size; (void)ws_size;
    const float* x    = (const float*)d_in[0];
    const int*   ei   = (const int*)d_in[1];
    const float* attr = (const float*)d_in[2];
    const float* W0 = (const float*)d_in[3];
    const float* R0 = (const float*)d_in[4];
    const float* B0 = (const float*)d_in[5];
    const float* W1 = (const float*)d_in[6];
    const float* R1 = (const float*)d_in[7];
    const float* B1 = (const float*)d_in[8];
    const float* W2 = (const float*)d_in[9];
    const float* R2 = (const float*)d_in[10];
    const float* B2 = (const float*)d_in[11];
    const int N = in_sizes[0] / 3;
    const int E = in_sizes[1] / 2;

    char* ws = (char*)d_ws;
    size_t off = 0;
    auto alloc = [&](size_t bytes) {
        size_t cur = off;
        off = (off + bytes + 255) & ~(size_t)255;
        return cur;
    };
    int* row_ptr = (int*)(ws + alloc((size_t)(N + 1) * 4));
    int* count   = (int*)(ws + alloc((size_t)N * 4));
    int* cursor  = (int*)(ws + alloc((size_t)N * 4));
    int* bsum    = (int*)(ws + alloc(64 * 4));
    int* boff    = (int*)(ws + alloc(64 * 4));
    int* tot     = (int*)(ws + alloc(4));
    int* s_meta  = (int*)(ws + alloc((size_t)E * 4));
    float* s_w   = (float*)(ws + alloc((size_t)E * 8 * 4));
    unsigned short* h_a = (unsigned short*)(ws + alloc((size_t)N * 64 * 2));
    unsigned short* h_b = (unsigned short*)(ws + alloc((size_t)N * 64 * 2));
    unsigned short* wb1 = (unsigned short*)(ws + alloc((size_t)4 * 56 * 64 * 8 * 2));
    unsigned short* wb2 = (unsigned short*)(ws + alloc((size_t)4 * 56 * 64 * 8 * 2));

    int nb = (N + 1023) / 1024;   // 49 <= 64

    hipMemsetAsync(count, 0, (size_t)N * 4, stream);
    count_kernel<<<(E + 255) / 256, 256, 0, stream>>>(ei, count, E);
    scan_tile_kernel<<<nb, 1024, 0, stream>>>(count, row_ptr, bsum, N);
    scan_bsum_kernel<<<1, 64, 0, stream>>>(bsum, boff, tot, nb);
    scan_add_kernel<<<nb, 1024, 0, stream>>>(row_ptr, boff, tot, cursor, N);
    basis_sort_kernel<<<(E + 255) / 256, 256, 0, stream>>>(ei, attr, count, cursor,
                                                           s_meta, s_w, E);
    build_wb2<<<(2 * 4 * 56 * 64 + 255) / 256, 256, 0, stream>>>(W1, R1, wb1,
                                                                 W2, R2, wb2);

    layer0_kernel<<<(N + 31) / 32, 256, 0, stream>>>(x, W0, R0, B0, row_ptr,
                                                     s_meta, s_w, h_a, N);
    layer64_kernel<false><<<(N + 3) / 4, 512, 0, stream>>>(h_a, wb1, B1, row_ptr,
                                                           s_meta, s_w, h_b, N);
    layer64_kernel<true><<<(N + 3) / 4, 512, 0, stream>>>(h_b, wb2, B2, row_ptr,
                                                          s_meta, s_w, d_out, N);
}

// Round 5
// 628.664 us; speedup vs baseline: 7.2848x; 1.1593x over previous
//
#include <hip/hip_runtime.h>
#include <cstdint>

// SplineConv MeshEncoder: 3 layers, K=3 DIM=3 M=27, dims 3->64->64->64.
// R18 = R15 base (R17 dual-wave split REVERTED: per-edge rate ~900cy
// unchanged => not chain-count-bound) + global_load_lds gather staging:
//   Evidence chain: R14 bytes-halving null; R15 VGPR-cap null (compiler
//   pins 60 VGPR, clusters each gather with its use -> one HBM round
//   trip per edge, ~900cy/edge == m126 HBM latency); R17 chain-doubling
//   null (same 900cy/edge). Conclusion: codegen serializes the gather
//   batch via register reuse. Fix: stage gathers through LDS with
//   __builtin_amdgcn_global_load_lds (NO destination VGPRs -> nothing
//   to serialize). Per 16-edge batch: 8 fire-and-forget loads (2 edges
//   per instr: half-wave each, 32 lanes x 4B = one 128B bf16 row),
//   one vmcnt(0), then ds_read_u16 + FMA from LDS.
//   R16 lesson kept: NO LDS atomics (CAS-loop disaster).

typedef __attribute__((ext_vector_type(8))) short short8;
typedef __attribute__((ext_vector_type(4))) float floatx4;

__device__ inline short f2bf(float f) {
    union { float f; unsigned u; } x; x.f = f;
    unsigned r = x.u + 0x7FFF + ((x.u >> 16) & 1);   // round-to-nearest-even
    return (short)(r >> 16);
}

__device__ inline float bf2f(unsigned short u) {
    union { unsigned u; float f; } x;
    x.u = ((unsigned)u) << 16;
    return x.f;
}

// ---------------- preprocessing (R10-proven) ----------------

__global__ void count_kernel(const int* __restrict__ ei, int* __restrict__ count, int E) {
    int e = blockIdx.x * blockDim.x + threadIdx.x;
    if (e < E) atomicAdd(&count[ei[E + e]], 1);
}

__global__ __launch_bounds__(1024) void scan_tile_kernel(const int* __restrict__ count,
                                                         int* __restrict__ row_ptr,
                                                         int* __restrict__ bsum, int N) {
    __shared__ int wsum[16];
    int tid = threadIdx.x, lane = tid & 63, wid = tid >> 6;
    int i = blockIdx.x * 1024 + tid;
    int v = (i < N) ? count[i] : 0;
    int incl = v;
#pragma unroll
    for (int off = 1; off < 64; off <<= 1) {
        int t = __shfl_up(incl, off, 64);
        if (lane >= off) incl += t;
    }
    if (lane == 63) wsum[wid] = incl;
    __syncthreads();
    if (tid < 16) {
        int w = wsum[tid];
#pragma unroll
        for (int off = 1; off < 16; off <<= 1) {
            int t = __shfl_up(w, off, 16);
            if ((tid & 15) >= off) w += t;
        }
        wsum[tid] = w;
    }
    __syncthreads();
    int waveoff = (wid > 0) ? wsum[wid - 1] : 0;
    if (i < N) row_ptr[i] = waveoff + incl - v;
    if (tid == 1023) bsum[blockIdx.x] = waveoff + incl;
}

__global__ __launch_bounds__(64) void scan_bsum_kernel(const int* __restrict__ bsum,
                                                       int* __restrict__ boff,
                                                       int* __restrict__ tot, int nb) {
    int tid = threadIdx.x;
    int v = (tid < nb) ? bsum[tid] : 0;
    int incl = v;
#pragma unroll
    for (int off = 1; off < 64; off <<= 1) {
        int t = __shfl_up(incl, off, 64);
        if (tid >= off) incl += t;
    }
    boff[tid] = incl - v;
    if (tid == 63) tot[0] = incl;
}

__global__ __launch_bounds__(1024) void scan_add_kernel(int* __restrict__ row_ptr,
                                                        const int* __restrict__ boff,
                                                        const int* __restrict__ tot,
                                                        int* __restrict__ cursor, int N) {
    int i = blockIdx.x * 1024 + threadIdx.x;
    if (i < N) {
        int r = row_ptr[i] + boff[blockIdx.x];
        row_ptr[i] = r;
        cursor[i] = r;
    }
    if (i == 0) row_ptr[N] = tot[0];
}

// Per edge: meta = src | base<<24, weights pre-scaled by 1/deg, scattered to
// dst-sorted position (two float4 stores). kidx = base + {0,1,3,4,9,10,12,13}[c].
__global__ void basis_sort_kernel(const int* __restrict__ ei, const float* __restrict__ attr,
                                  const int* __restrict__ count, int* __restrict__ cursor,
                                  int* __restrict__ s_meta, float* __restrict__ s_w, int E) {
    int e = blockIdx.x * blockDim.x + threadIdx.x;
    if (e >= E) return;
    int src = ei[e];
    int dst = ei[E + e];
    float f[3]; int i0[3];
#pragma unroll
    for (int d = 0; d < 3; d++) {
        float pos = attr[e * 3 + d] * 2.0f;          // K-1 = 2
        float fl = floorf(pos);
        fl = fminf(fmaxf(fl, 0.0f), 1.0f);           // clip to [0, K-2]
        i0[d] = (int)fl;
        f[d] = pos - fl;
    }
    int base = i0[0] + 3 * i0[1] + 9 * i0[2];        // in {0,1,3,4,9,10,12,13}
    float invd = 1.0f / fmaxf((float)count[dst], 1.0f);
    int p = atomicAdd(&cursor[dst], 1);
    s_meta[p] = src | (base << 24);
    float w[8];
#pragma unroll
    for (int c = 0; c < 8; c++) {
        float ww = 1.0f;
#pragma unroll
        for (int d = 0; d < 3; d++) {
            int off = (c >> d) & 1;
            ww *= off ? f[d] : (1.0f - f[d]);
        }
        w[c] = ww * invd;
    }
    floatx4 w03 = {w[0], w[1], w[2], w[3]};
    floatx4 w47 = {w[4], w[5], w[6], w[7]};
    *(floatx4*)(s_w + (size_t)p * 8) = w03;
    *(floatx4*)(s_w + (size_t)p * 8 + 4) = w47;
}

// Pre-swizzle [W(1728,64); Wr(64,64)] into bf16 MFMA B-frag order (R1-proven).
__global__ void build_wb2(const float* __restrict__ Wa, const float* __restrict__ Ra,
                          unsigned short* __restrict__ wba,
                          const float* __restrict__ Wb, const float* __restrict__ Rb,
                          unsigned short* __restrict__ wbb) {
    int idx0 = blockIdx.x * blockDim.x + threadIdx.x;   // [0, 2*4*56*64)
    int half = idx0 / (4 * 56 * 64);
    if (half >= 2) return;
    int idx = idx0 - half * (4 * 56 * 64);
    const float* W = half ? Wb : Wa;
    const float* Wr = half ? Rb : Ra;
    unsigned short* wb = half ? wbb : wba;
    int l = idx & 63;
    int c = (idx >> 6) % 56;
    int t = idx / (56 * 64);
    int q = l >> 4, o = t * 16 + (l & 15);
    short8 out;
#pragma unroll
    for (int j = 0; j < 8; j++) {
        int k = c * 32 + q * 8 + j;
        float v = (k < 1728) ? W[(size_t)k * 64 + o] : Wr[(size_t)(k - 1728) * 64 + o];
        out[j] = f2bf(v);
    }
    *(short8*)(wb + (size_t)idx * 8) = out;
}

// ---------------- layer 0 (CIN=3): dual-edge Phase A (unchanged) ----------------
__global__ __launch_bounds__(256) void layer0_kernel(
    const float* __restrict__ x, const float* __restrict__ W0,
    const float* __restrict__ Wr, const float* __restrict__ bias,
    const int* __restrict__ row_ptr, const int* __restrict__ s_meta,
    const float* __restrict__ s_w, unsigned short* __restrict__ h_out, int N) {
    constexpr int NPB = 32, KT = 84;
    __shared__ __align__(16) float acc[NPB * 2 * KT];   // 21.5 KB (dual copies)
    int tid = threadIdx.x, lane = tid & 63, wv = tid >> 6;
    int n0 = blockIdx.x * NPB;
    for (int k = tid; k < NPB * 2 * KT; k += 256) acc[k] = 0.0f;
    __syncthreads();

    int d = lane >> 5, hl = lane & 31;
    int c = hl / 3, i = hl - c * 3;
    bool act = (hl < 24);
    int cc = act ? c : 0;
    int coff = (c & 1) + 3 * ((c >> 1) & 1) + 9 * (c >> 2);   // corner offset

    for (int g2 = 0; g2 < 8; g2++) {
        int g = wv * 8 + g2;
        int n = n0 + g;
        if (n >= N) continue;
        if (lane < 3) acc[(g * 2) * KT + 81 + lane] = x[(size_t)n * 3 + lane];  // root
        int rs = row_ptr[n], re = row_ptr[n + 1];
        int npairs = (re - rs + 1) >> 1;
        float* accd = &acc[(g * 2 + d) * KT];
        for (int pb = 0; pb < npairs; pb += 4) {
            int metas[4]; float ws_[4], xs_[4];
#pragma unroll
            for (int j = 0; j < 4; j++) {            // clamp invalid -> rs (valid, w=0)
                int ej = rs + (pb + j) * 2 + d;
                bool v = (pb + j < npairs) && (ej < re);
                int ec = v ? ej : rs;
                metas[j] = s_meta[ec];
                float wv_ = s_w[(size_t)ec * 8 + cc];
                ws_[j] = v ? wv_ : 0.0f;
            }
#pragma unroll
            for (int j = 0; j < 4; j++)
                xs_[j] = x[(size_t)(metas[j] & 0xFFFFFF) * 3 + i];
#pragma unroll
            for (int j = 0; j < 4; j++) {
                int kidx = ((metas[j] >> 24) & 0xF) + coff;
                if (act) accd[kidx * 3 + i] += ws_[j] * xs_[j];
            }
        }
    }
    __syncthreads();

    // Phase B: o = lane, W in 84 registers; sum the dual acc copies.
    int o = lane;
    float wreg[KT];
#pragma unroll
    for (int k = 0; k < KT; k++)
        wreg[k] = (k < 81) ? W0[k * 64 + o] : Wr[(k - 81) * 64 + o];
    float bv = bias[o];
    for (int g = wv; g < NPB; g += 4) {
        int n = n0 + g;
        if (n >= N) break;
        float s = bv;
#pragma unroll
        for (int k4 = 0; k4 < KT; k4 += 4) {
            floatx4 a0 = *(const floatx4*)&acc[(g * 2) * KT + k4];
            floatx4 a1 = *(const floatx4*)&acc[(g * 2 + 1) * KT + k4];
            s += (a0.x + a1.x) * wreg[k4] + (a0.y + a1.y) * wreg[k4 + 1]
               + (a0.z + a1.z) * wreg[k4 + 2] + (a0.w + a1.w) * wreg[k4 + 3];
        }
        h_out[(size_t)n * 64 + o] = (unsigned short)f2bf(fmaxf(s, 0.0f));
    }
}

// ---------------- 64-ch layers: global_load_lds-staged Phase A ----------------
// Wave wvu owns node n0+wvu. Per 16-edge batch: 8 fire-and-forget
// global_load_lds (no dest VGPRs; half-wave per edge row), vmcnt(0),
// then ds_read_u16 + 8-FMA switch per edge. Phase B unchanged from R12.
template <bool OUTF32>
__global__ __launch_bounds__(512) void layer64_kernel(
    const unsigned short* __restrict__ h_in, const unsigned short* __restrict__ wb,
    const float* __restrict__ bias, const int* __restrict__ row_ptr,
    const int* __restrict__ s_meta, const float* __restrict__ s_w,
    void* __restrict__ h_out, int N) {
    constexpr int NPB = 8;
    constexpr int STR = 1808;            // shorts; dword-stride 904 = even bank spread
    __shared__ __align__(16) unsigned short accb[NPB * STR];     // 28,928 B
    __shared__ __align__(16) unsigned short stage[NPB * 1024];   // 16 KB gather stage
    int tid = threadIdx.x, lane = tid & 63;
    int wvu = __builtin_amdgcn_readfirstlane(tid >> 6);   // uniform wave id 0..7
    int n0 = blockIdx.x * NPB;

#define EDGE_FMA(EIDX, XJ) do { \
    const float* wp = s_w + (size_t)(EIDX) * 8; \
    float w0 = wp[0], w1 = wp[1], w2 = wp[2], w3 = wp[3]; \
    float w4 = wp[4], w5 = wp[5], w6 = wp[6], w7 = wp[7]; \
    float xj = (XJ); \
    switch (bases) { \
    case 0:  acc[0]+=w0*xj;  acc[1]+=w1*xj;  acc[3]+=w2*xj;  acc[4]+=w3*xj; \
             acc[9]+=w4*xj;  acc[10]+=w5*xj; acc[12]+=w6*xj; acc[13]+=w7*xj; break; \
    case 1:  acc[1]+=w0*xj;  acc[2]+=w1*xj;  acc[4]+=w2*xj;  acc[5]+=w3*xj; \
             acc[10]+=w4*xj; acc[11]+=w5*xj; acc[13]+=w6*xj; acc[14]+=w7*xj; break; \
    case 3:  acc[3]+=w0*xj;  acc[4]+=w1*xj;  acc[6]+=w2*xj;  acc[7]+=w3*xj; \
             acc[12]+=w4*xj; acc[13]+=w5*xj; acc[15]+=w6*xj; acc[16]+=w7*xj; break; \
    case 4:  acc[4]+=w0*xj;  acc[5]+=w1*xj;  acc[7]+=w2*xj;  acc[8]+=w3*xj; \
             acc[13]+=w4*xj; acc[14]+=w5*xj; acc[16]+=w6*xj; acc[17]+=w7*xj; break; \
    case 9:  acc[9]+=w0*xj;  acc[10]+=w1*xj; acc[12]+=w2*xj; acc[13]+=w3*xj; \
             acc[18]+=w4*xj; acc[19]+=w5*xj; acc[21]+=w6*xj; acc[22]+=w7*xj; break; \
    case 10: acc[10]+=w0*xj; acc[11]+=w1*xj; acc[13]+=w2*xj; acc[14]+=w3*xj; \
             acc[19]+=w4*xj; acc[20]+=w5*xj; acc[22]+=w6*xj; acc[23]+=w7*xj; break; \
    case 12: acc[12]+=w0*xj; acc[13]+=w1*xj; acc[15]+=w2*xj; acc[16]+=w3*xj; \
             acc[21]+=w4*xj; acc[22]+=w5*xj; acc[24]+=w6*xj; acc[25]+=w7*xj; break; \
    default: acc[13]+=w0*xj; acc[14]+=w1*xj; acc[16]+=w2*xj; acc[17]+=w3*xj; \
             acc[22]+=w4*xj; acc[23]+=w5*xj; acc[25]+=w6*xj; acc[26]+=w7*xj; break; } \
} while (0)

    // ---- Phase A ----
    {
        int n = n0 + wvu;
        unsigned short* arowb = &accb[wvu * STR];
        unsigned short* stg = &stage[wvu * 1024];   // 16 edges x 64 ch (2 KB)
        if (n >= N) {   // tail hygiene: zero the row so MFMA sees no stale LDS
            for (int k = lane; k < 1792; k += 64) arowb[k] = 0;
        } else {
            float acc[27];
#pragma unroll
            for (int m = 0; m < 27; m++) acc[m] = 0.0f;
            int rs = row_ptr[n], re = row_ptr[n + 1];
            int cnt = re - rs;
            for (int b0 = 0; b0 < cnt; b0 += 16) {
                int rem = cnt - b0;
                int nb = (rem < 16) ? rem : 16;
                // issue 8 dest-register-free gathers (16 edge slots, clamped)
#pragma unroll
                for (int jj = 0; jj < 8; jj++) {
                    int eA = (2 * jj < rem) ? (rs + b0 + 2 * jj) : rs;
                    int eB = (2 * jj + 1 < rem) ? (rs + b0 + 2 * jj + 1) : rs;
                    int mA = s_meta[eA] & 0xFFFFFF;
                    int mB = s_meta[eB] & 0xFFFFFF;
                    int m = (lane < 32) ? mA : mB;
                    const unsigned short* src =
                        h_in + (size_t)m * 64 + ((lane & 31) << 1);
                    __builtin_amdgcn_global_load_lds(
                        (const __attribute__((address_space(1))) unsigned int*)src,
                        (__attribute__((address_space(3))) unsigned int*)(stg + jj * 128),
                        4, 0, 0);
                }
                asm volatile("s_waitcnt vmcnt(0)" ::: "memory");
                // process the staged edges, 4 at a time (ds_read pipelining)
                for (int j4 = 0; j4 < nb; j4 += 4) {
                    float xjs[4];
#pragma unroll
                    for (int u = 0; u < 4; u++)
                        xjs[u] = bf2f(stg[(j4 + u) * 64 + lane]);
#pragma unroll
                    for (int u = 0; u < 4; u++) {
                        int j = j4 + u;
                        if (j < nb) {
                            int meta = s_meta[rs + b0 + j];
                            int bases = (meta >> 24) & 0xF;
                            EDGE_FMA(rs + b0 + j, xjs[u]);
                        }
                    }
                }
                asm volatile("" ::: "memory");   // order: reads before next issue
            }
#pragma unroll
            for (int m = 0; m < 27; m++)
                arowb[m * 64 + lane] = (unsigned short)f2bf(acc[m]);
            arowb[1728 + lane] = h_in[(size_t)n * 64 + lane];   // already bf16
        }
    }
#undef EDGE_FMA
    __syncthreads();

    // ---- Phase B: all 8 waves, 2-way split-K (broadcast A reads) ----
    {
        int t = wvu & 3;
        int hf = wvu >> 2;
        const unsigned short* ap = accb + (lane & 7) * STR + ((lane >> 4) * 8);
        floatx4 facc = {0.0f, 0.0f, 0.0f, 0.0f};
        const unsigned short* wbp = wb + ((size_t)(t * 56) * 64 + lane) * 8;
#pragma unroll
        for (int ci = 0; ci < 28; ci++) {
            int c = hf * 28 + ci;
            short8 af = *(const short8*)(ap + c * 32);
            short8 bfr = *(const short8*)(wbp + (size_t)c * 64 * 8);
            facc = __builtin_amdgcn_mfma_f32_16x16x32_bf16(af, bfr, facc, 0, 0, 0);
        }
        __syncthreads();               // all MFMA reads of accb complete
        float* pf = (float*)accb;      // 8 waves x 256 floats = 8KB (fits)
#pragma unroll
        for (int r = 0; r < 4; r++) pf[wvu * 256 + r * 64 + lane] = facc[r];
        __syncthreads();
        if (wvu < 4) {
            int o = t * 16 + (lane & 15);
            float bv = bias[o];
#pragma unroll
            for (int r = 0; r < 4; r++) {
                int m = (lane >> 4) * 4 + r;
                if (m < 8) {
                    int n = n0 + m;
                    if (n < N) {
                        float s = pf[t * 256 + r * 64 + lane]
                                + pf[(t + 4) * 256 + r * 64 + lane];
                        float val = fmaxf(s + bv, 0.0f);
                        if (OUTF32) {
                            ((float*)h_out)[(size_t)n * 64 + o] = val;
                        } else {
                            ((unsigned short*)h_out)[(size_t)n * 64 + o] =
                                (unsigned short)f2bf(val);
                        }
                    }
                }
            }
        }
    }
}

extern "C" void kernel_launch(void* const* d_in, const int* in_sizes, int n_in,
                              void* d_out, int out_size, void* d_ws, size_t ws_size,
                              hipStream_t stream) {
    (void)n_in; (void)out_size; (void)ws_size;
    const float* x    = (const float*)d_in[0];
    const int*   ei   = (const int*)d_in[1];
    const float* attr = (const float*)d_in[2];
    const float* W0 = (const float*)d_in[3];
    const float* R0 = (const float*)d_in[4];
    const float* B0 = (const float*)d_in[5];
    const float* W1 = (const float*)d_in[6];
    const float* R1 = (const float*)d_in[7];
    const float* B1 = (const float*)d_in[8];
    const float* W2 = (const float*)d_in[9];
    const float* R2 = (const float*)d_in[10];
    const float* B2 = (const float*)d_in[11];
    const int N = in_sizes[0] / 3;
    const int E = in_sizes[1] / 2;

    char* ws = (char*)d_ws;
    size_t off = 0;
    auto alloc = [&](size_t bytes) {
        size_t cur = off;
        off = (off + bytes + 255) & ~(size_t)255;
        return cur;
    };
    int* row_ptr = (int*)(ws + alloc((size_t)(N + 1) * 4));
    int* count   = (int*)(ws + alloc((size_t)N * 4));
    int* cursor  = (int*)(ws + alloc((size_t)N * 4));
    int* bsum    = (int*)(ws + alloc(64 * 4));
    int* boff    = (int*)(ws + alloc(64 * 4));
    int* tot     = (int*)(ws + alloc(4));
    int* s_meta  = (int*)(ws + alloc((size_t)E * 4));
    float* s_w   = (float*)(ws + alloc((size_t)E * 8 * 4));
    unsigned short* h_a = (unsigned short*)(ws + alloc((size_t)N * 64 * 2));
    unsigned short* h_b = (unsigned short*)(ws + alloc((size_t)N * 64 * 2));
    unsigned short* wb1 = (unsigned short*)(ws + alloc((size_t)4 * 56 * 64 * 8 * 2));
    unsigned short* wb2 = (unsigned short*)(ws + alloc((size_t)4 * 56 * 64 * 8 * 2));

    int nb = (N + 1023) / 1024;   // 49 <= 64

    hipMemsetAsync(count, 0, (size_t)N * 4, stream);
    count_kernel<<<(E + 255) / 256, 256, 0, stream>>>(ei, count, E);
    scan_tile_kernel<<<nb, 1024, 0, stream>>>(count, row_ptr, bsum, N);
    scan_bsum_kernel<<<1, 64, 0, stream>>>(bsum, boff, tot, nb);
    scan_add_kernel<<<nb, 1024, 0, stream>>>(row_ptr, boff, tot, cursor, N);
    basis_sort_kernel<<<(E + 255) / 256, 256, 0, stream>>>(ei, attr, count, cursor,
                                                           s_meta, s_w, E);
    build_wb2<<<(2 * 4 * 56 * 64 + 255) / 256, 256, 0, stream>>>(W1, R1, wb1,
                                                                 W2, R2, wb2);

    layer0_kernel<<<(N + 31) / 32, 256, 0, stream>>>(x, W0, R0, B0, row_ptr,
                                                     s_meta, s_w, h_a, N);
    layer64_kernel<false><<<(N + 7) / 8, 512, 0, stream>>>(h_a, wb1, B1, row_ptr,
                                                           s_meta, s_w, h_b, N);
    layer64_kernel<true><<<(N + 7) / 8, 512, 0, stream>>>(h_b, wb2, B2, row_ptr,
                                                          s_meta, s_w, d_out, N);
}

// Round 6
// 628.262 us; speedup vs baseline: 7.2894x; 1.0006x over previous
//
#include <hip/hip_runtime.h>
#include <cstdint>

// SplineConv MeshEncoder: 3 layers, K=3 DIM=3 M=27, dims 3->64->64->64.
// R19 = R18 + three Phase-A changes in layer64:
//  (1) readfirstlane(bases): VALUBusy=60% at 214us implies ~100+ VALU
//      instrs/edge -- consistent with the switch(bases) compiled DIVERGENT
//      (all 8 cases exec-masked = 64 FMA/edge). Force SGPR + uniform
//      scalar-branch jump table.
//  (2) s_w staged to LDS per 64-edge window (2x global_load_lds size16);
//      processing reads w via broadcast ds_read_b128 -- removes per-edge
//      global w loads from the dependent chain.
//  (3) double-buffered feature staging with counted vmcnt(4): process
//      batch b-1 while batch b is in flight (T4 pattern). Parity buffers
//      make compiler reordering benign (same-buffer aliasing forces order).
//  R16 lesson kept: NO LDS atomics. R14 kept: bf16 h. R18 kept: gather
//  staging via global_load_lds.

typedef __attribute__((ext_vector_type(8))) short short8;
typedef __attribute__((ext_vector_type(4))) float floatx4;

__device__ inline short f2bf(float f) {
    union { float f; unsigned u; } x; x.f = f;
    unsigned r = x.u + 0x7FFF + ((x.u >> 16) & 1);   // round-to-nearest-even
    return (short)(r >> 16);
}

__device__ inline float bf2f(unsigned short u) {
    union { unsigned u; float f; } x;
    x.u = ((unsigned)u) << 16;
    return x.f;
}

// ---------------- preprocessing (R10-proven) ----------------

__global__ void count_kernel(const int* __restrict__ ei, int* __restrict__ count, int E) {
    int e = blockIdx.x * blockDim.x + threadIdx.x;
    if (e < E) atomicAdd(&count[ei[E + e]], 1);
}

__global__ __launch_bounds__(1024) void scan_tile_kernel(const int* __restrict__ count,
                                                         int* __restrict__ row_ptr,
                                                         int* __restrict__ bsum, int N) {
    __shared__ int wsum[16];
    int tid = threadIdx.x, lane = tid & 63, wid = tid >> 6;
    int i = blockIdx.x * 1024 + tid;
    int v = (i < N) ? count[i] : 0;
    int incl = v;
#pragma unroll
    for (int off = 1; off < 64; off <<= 1) {
        int t = __shfl_up(incl, off, 64);
        if (lane >= off) incl += t;
    }
    if (lane == 63) wsum[wid] = incl;
    __syncthreads();
    if (tid < 16) {
        int w = wsum[tid];
#pragma unroll
        for (int off = 1; off < 16; off <<= 1) {
            int t = __shfl_up(w, off, 16);
            if ((tid & 15) >= off) w += t;
        }
        wsum[tid] = w;
    }
    __syncthreads();
    int waveoff = (wid > 0) ? wsum[wid - 1] : 0;
    if (i < N) row_ptr[i] = waveoff + incl - v;
    if (tid == 1023) bsum[blockIdx.x] = waveoff + incl;
}

__global__ __launch_bounds__(64) void scan_bsum_kernel(const int* __restrict__ bsum,
                                                       int* __restrict__ boff,
                                                       int* __restrict__ tot, int nb) {
    int tid = threadIdx.x;
    int v = (tid < nb) ? bsum[tid] : 0;
    int incl = v;
#pragma unroll
    for (int off = 1; off < 64; off <<= 1) {
        int t = __shfl_up(incl, off, 64);
        if (tid >= off) incl += t;
    }
    boff[tid] = incl - v;
    if (tid == 63) tot[0] = incl;
}

__global__ __launch_bounds__(1024) void scan_add_kernel(int* __restrict__ row_ptr,
                                                        const int* __restrict__ boff,
                                                        const int* __restrict__ tot,
                                                        int* __restrict__ cursor, int N) {
    int i = blockIdx.x * 1024 + threadIdx.x;
    if (i < N) {
        int r = row_ptr[i] + boff[blockIdx.x];
        row_ptr[i] = r;
        cursor[i] = r;
    }
    if (i == 0) row_ptr[N] = tot[0];
}

// Per edge: meta = src | base<<24, weights pre-scaled by 1/deg, scattered to
// dst-sorted position (two float4 stores). kidx = base + {0,1,3,4,9,10,12,13}[c].
__global__ void basis_sort_kernel(const int* __restrict__ ei, const float* __restrict__ attr,
                                  const int* __restrict__ count, int* __restrict__ cursor,
                                  int* __restrict__ s_meta, float* __restrict__ s_w, int E) {
    int e = blockIdx.x * blockDim.x + threadIdx.x;
    if (e >= E) return;
    int src = ei[e];
    int dst = ei[E + e];
    float f[3]; int i0[3];
#pragma unroll
    for (int d = 0; d < 3; d++) {
        float pos = attr[e * 3 + d] * 2.0f;          // K-1 = 2
        float fl = floorf(pos);
        fl = fminf(fmaxf(fl, 0.0f), 1.0f);           // clip to [0, K-2]
        i0[d] = (int)fl;
        f[d] = pos - fl;
    }
    int base = i0[0] + 3 * i0[1] + 9 * i0[2];        // in {0,1,3,4,9,10,12,13}
    float invd = 1.0f / fmaxf((float)count[dst], 1.0f);
    int p = atomicAdd(&cursor[dst], 1);
    s_meta[p] = src | (base << 24);
    float w[8];
#pragma unroll
    for (int c = 0; c < 8; c++) {
        float ww = 1.0f;
#pragma unroll
        for (int d = 0; d < 3; d++) {
            int off = (c >> d) & 1;
            ww *= off ? f[d] : (1.0f - f[d]);
        }
        w[c] = ww * invd;
    }
    floatx4 w03 = {w[0], w[1], w[2], w[3]};
    floatx4 w47 = {w[4], w[5], w[6], w[7]};
    *(floatx4*)(s_w + (size_t)p * 8) = w03;
    *(floatx4*)(s_w + (size_t)p * 8 + 4) = w47;
}

// Pre-swizzle [W(1728,64); Wr(64,64)] into bf16 MFMA B-frag order (R1-proven).
__global__ void build_wb2(const float* __restrict__ Wa, const float* __restrict__ Ra,
                          unsigned short* __restrict__ wba,
                          const float* __restrict__ Wb, const float* __restrict__ Rb,
                          unsigned short* __restrict__ wbb) {
    int idx0 = blockIdx.x * blockDim.x + threadIdx.x;   // [0, 2*4*56*64)
    int half = idx0 / (4 * 56 * 64);
    if (half >= 2) return;
    int idx = idx0 - half * (4 * 56 * 64);
    const float* W = half ? Wb : Wa;
    const float* Wr = half ? Rb : Ra;
    unsigned short* wb = half ? wbb : wba;
    int l = idx & 63;
    int c = (idx >> 6) % 56;
    int t = idx / (56 * 64);
    int q = l >> 4, o = t * 16 + (l & 15);
    short8 out;
#pragma unroll
    for (int j = 0; j < 8; j++) {
        int k = c * 32 + q * 8 + j;
        float v = (k < 1728) ? W[(size_t)k * 64 + o] : Wr[(size_t)(k - 1728) * 64 + o];
        out[j] = f2bf(v);
    }
    *(short8*)(wb + (size_t)idx * 8) = out;
}

// ---------------- layer 0 (CIN=3): dual-edge Phase A (unchanged) ----------------
__global__ __launch_bounds__(256) void layer0_kernel(
    const float* __restrict__ x, const float* __restrict__ W0,
    const float* __restrict__ Wr, const float* __restrict__ bias,
    const int* __restrict__ row_ptr, const int* __restrict__ s_meta,
    const float* __restrict__ s_w, unsigned short* __restrict__ h_out, int N) {
    constexpr int NPB = 32, KT = 84;
    __shared__ __align__(16) float acc[NPB * 2 * KT];   // 21.5 KB (dual copies)
    int tid = threadIdx.x, lane = tid & 63, wv = tid >> 6;
    int n0 = blockIdx.x * NPB;
    for (int k = tid; k < NPB * 2 * KT; k += 256) acc[k] = 0.0f;
    __syncthreads();

    int d = lane >> 5, hl = lane & 31;
    int c = hl / 3, i = hl - c * 3;
    bool act = (hl < 24);
    int cc = act ? c : 0;
    int coff = (c & 1) + 3 * ((c >> 1) & 1) + 9 * (c >> 2);   // corner offset

    for (int g2 = 0; g2 < 8; g2++) {
        int g = wv * 8 + g2;
        int n = n0 + g;
        if (n >= N) continue;
        if (lane < 3) acc[(g * 2) * KT + 81 + lane] = x[(size_t)n * 3 + lane];  // root
        int rs = row_ptr[n], re = row_ptr[n + 1];
        int npairs = (re - rs + 1) >> 1;
        float* accd = &acc[(g * 2 + d) * KT];
        for (int pb = 0; pb < npairs; pb += 4) {
            int metas[4]; float ws_[4], xs_[4];
#pragma unroll
            for (int j = 0; j < 4; j++) {            // clamp invalid -> rs (valid, w=0)
                int ej = rs + (pb + j) * 2 + d;
                bool v = (pb + j < npairs) && (ej < re);
                int ec = v ? ej : rs;
                metas[j] = s_meta[ec];
                float wv_ = s_w[(size_t)ec * 8 + cc];
                ws_[j] = v ? wv_ : 0.0f;
            }
#pragma unroll
            for (int j = 0; j < 4; j++)
                xs_[j] = x[(size_t)(metas[j] & 0xFFFFFF) * 3 + i];
#pragma unroll
            for (int j = 0; j < 4; j++) {
                int kidx = ((metas[j] >> 24) & 0xF) + coff;
                if (act) accd[kidx * 3 + i] += ws_[j] * xs_[j];
            }
        }
    }
    __syncthreads();

    // Phase B: o = lane, W in 84 registers; sum the dual acc copies.
    int o = lane;
    float wreg[KT];
#pragma unroll
    for (int k = 0; k < KT; k++)
        wreg[k] = (k < 81) ? W0[k * 64 + o] : Wr[(k - 81) * 64 + o];
    float bv = bias[o];
    for (int g = wv; g < NPB; g += 4) {
        int n = n0 + g;
        if (n >= N) break;
        float s = bv;
#pragma unroll
        for (int k4 = 0; k4 < KT; k4 += 4) {
            floatx4 a0 = *(const floatx4*)&acc[(g * 2) * KT + k4];
            floatx4 a1 = *(const floatx4*)&acc[(g * 2 + 1) * KT + k4];
            s += (a0.x + a1.x) * wreg[k4] + (a0.y + a1.y) * wreg[k4 + 1]
               + (a0.z + a1.z) * wreg[k4 + 2] + (a0.w + a1.w) * wreg[k4 + 3];
        }
        h_out[(size_t)n * 64 + o] = (unsigned short)f2bf(fmaxf(s, 0.0f));
    }
}

// ---------------- 64-ch layers: uniform-switch + dbuf-staged Phase A ----------------
template <bool OUTF32>
__global__ __launch_bounds__(512) void layer64_kernel(
    const unsigned short* __restrict__ h_in, const unsigned short* __restrict__ wb,
    const float* __restrict__ bias, const int* __restrict__ row_ptr,
    const int* __restrict__ s_meta, const float* __restrict__ s_w,
    void* __restrict__ h_out, int N) {
    constexpr int NPB = 8;
    constexpr int STR = 1808;            // shorts; dword-stride 904 = even bank spread
    __shared__ __align__(16) unsigned short accb[NPB * STR];     // 28,928 B
    __shared__ __align__(16) unsigned short stageX[NPB * 1024];  // 16 KB: 2buf x 8edge x 64ch
    __shared__ __align__(16) float stageW[NPB * 512];            // 16 KB: 64edge x 8 w
    int tid = threadIdx.x, lane = tid & 63;
    int wvu = __builtin_amdgcn_readfirstlane(tid >> 6);   // uniform wave id 0..7
    int n0 = blockIdx.x * NPB;

#define EDGE_FMA8(BASES, WA, WB, XJ) do { \
    float xj = (XJ); \
    float w0 = (WA).x, w1 = (WA).y, w2 = (WA).z, w3 = (WA).w; \
    float w4 = (WB).x, w5 = (WB).y, w6 = (WB).z, w7 = (WB).w; \
    switch (BASES) { \
    case 0:  acc[0]+=w0*xj;  acc[1]+=w1*xj;  acc[3]+=w2*xj;  acc[4]+=w3*xj; \
             acc[9]+=w4*xj;  acc[10]+=w5*xj; acc[12]+=w6*xj; acc[13]+=w7*xj; break; \
    case 1:  acc[1]+=w0*xj;  acc[2]+=w1*xj;  acc[4]+=w2*xj;  acc[5]+=w3*xj; \
             acc[10]+=w4*xj; acc[11]+=w5*xj; acc[13]+=w6*xj; acc[14]+=w7*xj; break; \
    case 3:  acc[3]+=w0*xj;  acc[4]+=w1*xj;  acc[6]+=w2*xj;  acc[7]+=w3*xj; \
             acc[12]+=w4*xj; acc[13]+=w5*xj; acc[15]+=w6*xj; acc[16]+=w7*xj; break; \
    case 4:  acc[4]+=w0*xj;  acc[5]+=w1*xj;  acc[7]+=w2*xj;  acc[8]+=w3*xj; \
             acc[13]+=w4*xj; acc[14]+=w5*xj; acc[16]+=w6*xj; acc[17]+=w7*xj; break; \
    case 9:  acc[9]+=w0*xj;  acc[10]+=w1*xj; acc[12]+=w2*xj; acc[13]+=w3*xj; \
             acc[18]+=w4*xj; acc[19]+=w5*xj; acc[21]+=w6*xj; acc[22]+=w7*xj; break; \
    case 10: acc[10]+=w0*xj; acc[11]+=w1*xj; acc[13]+=w2*xj; acc[14]+=w3*xj; \
             acc[19]+=w4*xj; acc[20]+=w5*xj; acc[22]+=w6*xj; acc[23]+=w7*xj; break; \
    case 12: acc[12]+=w0*xj; acc[13]+=w1*xj; acc[15]+=w2*xj; acc[16]+=w3*xj; \
             acc[21]+=w4*xj; acc[22]+=w5*xj; acc[24]+=w6*xj; acc[25]+=w7*xj; break; \
    default: acc[13]+=w0*xj; acc[14]+=w1*xj; acc[16]+=w2*xj; acc[17]+=w3*xj; \
             acc[22]+=w4*xj; acc[23]+=w5*xj; acc[25]+=w6*xj; acc[26]+=w7*xj; break; } \
} while (0)

// Process staged batch BI (uniform control; w from LDS broadcast; bases scalar).
#define PROCESS(BI) do { \
    const unsigned short* sb = stgx + ((BI) & 1) * 512; \
    int nbj = wrem - (BI) * 8; if (nbj > 8) nbj = 8; \
    int ep = rs + wb + (BI) * 8; \
    _Pragma("unroll 2") \
    for (int j = 0; j < nbj; j++) { \
        float xjv = bf2f(sb[j * 64 + lane]); \
        const float* wp = stgw + ((BI) * 8 + j) * 8; \
        floatx4 wva = *(const floatx4*)wp; \
        floatx4 wvb = *(const floatx4*)(wp + 4); \
        int bases = __builtin_amdgcn_readfirstlane((s_meta[ep + j] >> 24) & 0xF); \
        EDGE_FMA8(bases, wva, wvb, xjv); \
    } \
} while (0)

    // ---- Phase A ----
    {
        int n = n0 + wvu;
        unsigned short* arowb = &accb[wvu * STR];
        unsigned short* stgx = &stageX[wvu * 1024];
        float* stgw = &stageW[wvu * 512];
        if (n >= N) {   // tail hygiene: zero the row so MFMA sees no stale LDS
            for (int k = lane; k < 1792; k += 64) arowb[k] = 0;
        } else {
            float acc[27];
#pragma unroll
            for (int m = 0; m < 27; m++) acc[m] = 0.0f;
            int rs = row_ptr[n], re = row_ptr[n + 1];
            int cnt = re - rs;
            for (int wb = 0; wb < cnt; wb += 64) {
                int wrem = cnt - wb; if (wrem > 64) wrem = 64;
                // stage w window: 2 x size16 = 2KB = 64 edges (over-read safe in ws)
                {
                    const float* ws = s_w + (size_t)(rs + wb) * 8 + lane * 4;
                    __builtin_amdgcn_global_load_lds(
                        (const __attribute__((address_space(1))) unsigned int*)ws,
                        (__attribute__((address_space(3))) unsigned int*)stgw, 16, 0, 0);
                    __builtin_amdgcn_global_load_lds(
                        (const __attribute__((address_space(1))) unsigned int*)(ws + 256),
                        (__attribute__((address_space(3))) unsigned int*)(stgw + 256),
                        16, 0, 0);
                }
                int nbat = (wrem + 7) >> 3;
                for (int b = 0; b < nbat; b++) {
                    // issue features for batch b (4 instrs, 8 edges, clamped)
                    {
                        unsigned short* dst = stgx + (b & 1) * 512;
                        int ebase = rs + wb + b * 8;
#pragma unroll
                        for (int jj = 0; jj < 4; jj++) {
                            int eA = ebase + 2 * jj;     if (eA >= re) eA = re - 1;
                            int eB = ebase + 2 * jj + 1; if (eB >= re) eB = re - 1;
                            int mA = s_meta[eA] & 0xFFFFFF;
                            int mB = s_meta[eB] & 0xFFFFFF;
                            int m = (lane < 32) ? mA : mB;
                            const unsigned short* src =
                                h_in + (size_t)m * 64 + ((lane & 31) << 1);
                            __builtin_amdgcn_global_load_lds(
                                (const __attribute__((address_space(1))) unsigned int*)src,
                                (__attribute__((address_space(3))) unsigned int*)(dst + jj * 128),
                                4, 0, 0);
                        }
                    }
                    if (b > 0) {
                        asm volatile("s_waitcnt vmcnt(4)" ::: "memory");
                        PROCESS(b - 1);
                    }
                }
                asm volatile("s_waitcnt vmcnt(0)" ::: "memory");
                PROCESS(nbat - 1);
            }
#pragma unroll
            for (int m = 0; m < 27; m++)
                arowb[m * 64 + lane] = (unsigned short)f2bf(acc[m]);
            arowb[1728 + lane] = h_in[(size_t)n * 64 + lane];   // already bf16
        }
    }
#undef PROCESS
#undef EDGE_FMA8
    __syncthreads();

    // ---- Phase B: all 8 waves, 2-way split-K (broadcast A reads) ----
    {
        int t = wvu & 3;
        int hf = wvu >> 2;
        const unsigned short* ap = accb + (lane & 7) * STR + ((lane >> 4) * 8);
        floatx4 facc = {0.0f, 0.0f, 0.0f, 0.0f};
        const unsigned short* wbp = wb + ((size_t)(t * 56) * 64 + lane) * 8;
#pragma unroll
        for (int ci = 0; ci < 28; ci++) {
            int c = hf * 28 + ci;
            short8 af = *(const short8*)(ap + c * 32);
            short8 bfr = *(const short8*)(wbp + (size_t)c * 64 * 8);
            facc = __builtin_amdgcn_mfma_f32_16x16x32_bf16(af, bfr, facc, 0, 0, 0);
        }
        __syncthreads();               // all MFMA reads of accb complete
        float* pf = (float*)accb;      // 8 waves x 256 floats = 8KB (fits)
#pragma unroll
        for (int r = 0; r < 4; r++) pf[wvu * 256 + r * 64 + lane] = facc[r];
        __syncthreads();
        if (wvu < 4) {
            int o = t * 16 + (lane & 15);
            float bv = bias[o];
#pragma unroll
            for (int r = 0; r < 4; r++) {
                int m = (lane >> 4) * 4 + r;
                if (m < 8) {
                    int n = n0 + m;
                    if (n < N) {
                        float s = pf[t * 256 + r * 64 + lane]
                                + pf[(t + 4) * 256 + r * 64 + lane];
                        float val = fmaxf(s + bv, 0.0f);
                        if (OUTF32) {
                            ((float*)h_out)[(size_t)n * 64 + o] = val;
                        } else {
                            ((unsigned short*)h_out)[(size_t)n * 64 + o] =
                                (unsigned short)f2bf(val);
                        }
                    }
                }
            }
        }
    }
}

extern "C" void kernel_launch(void* const* d_in, const int* in_sizes, int n_in,
                              void* d_out, int out_size, void* d_ws, size_t ws_size,
                              hipStream_t stream) {
    (void)n_in; (void)out_size; (void)ws_size;
    const float* x    = (const float*)d_in[0];
    const int*   ei   = (const int*)d_in[1];
    const float* attr = (const float*)d_in[2];
    const float* W0 = (const float*)d_in[3];
    const float* R0 = (const float*)d_in[4];
    const float* B0 = (const float*)d_in[5];
    const float* W1 = (const float*)d_in[6];
    const float* R1 = (const float*)d_in[7];
    const float* B1 = (const float*)d_in[8];
    const float* W2 = (const float*)d_in[9];
    const float* R2 = (const float*)d_in[10];
    const float* B2 = (const float*)d_in[11];
    const int N = in_sizes[0] / 3;
    const int E = in_sizes[1] / 2;

    char* ws = (char*)d_ws;
    size_t off = 0;
    auto alloc = [&](size_t bytes) {
        size_t cur = off;
        off = (off + bytes + 255) & ~(size_t)255;
        return cur;
    };
    int* row_ptr = (int*)(ws + alloc((size_t)(N + 1) * 4));
    int* count   = (int*)(ws + alloc((size_t)N * 4));
    int* cursor  = (int*)(ws + alloc((size_t)N * 4));
    int* bsum    = (int*)(ws + alloc(64 * 4));
    int* boff    = (int*)(ws + alloc(64 * 4));
    int* tot     = (int*)(ws + alloc(4));
    int* s_meta  = (int*)(ws + alloc((size_t)E * 4));
    float* s_w   = (float*)(ws + alloc((size_t)E * 8 * 4));
    unsigned short* h_a = (unsigned short*)(ws + alloc((size_t)N * 64 * 2));
    unsigned short* h_b = (unsigned short*)(ws + alloc((size_t)N * 64 * 2));
    unsigned short* wb1 = (unsigned short*)(ws + alloc((size_t)4 * 56 * 64 * 8 * 2));
    unsigned short* wb2 = (unsigned short*)(ws + alloc((size_t)4 * 56 * 64 * 8 * 2));

    int nb = (N + 1023) / 1024;   // 49 <= 64

    hipMemsetAsync(count, 0, (size_t)N * 4, stream);
    count_kernel<<<(E + 255) / 256, 256, 0, stream>>>(ei, count, E);
    scan_tile_kernel<<<nb, 1024, 0, stream>>>(count, row_ptr, bsum, N);
    scan_bsum_kernel<<<1, 64, 0, stream>>>(bsum, boff, tot, nb);
    scan_add_kernel<<<nb, 1024, 0, stream>>>(row_ptr, boff, tot, cursor, N);
    basis_sort_kernel<<<(E + 255) / 256, 256, 0, stream>>>(ei, attr, count, cursor,
                                                           s_meta, s_w, E);
    build_wb2<<<(2 * 4 * 56 * 64 + 255) / 256, 256, 0, stream>>>(W1, R1, wb1,
                                                                 W2, R2, wb2);

    layer0_kernel<<<(N + 31) / 32, 256, 0, stream>>>(x, W0, R0, B0, row_ptr,
                                                     s_meta, s_w, h_a, N);
    layer64_kernel<false><<<(N + 7) / 8, 512, 0, stream>>>(h_a, wb1, B1, row_ptr,
                                                           s_meta, s_w, h_b, N);
    layer64_kernel<true><<<(N + 7) / 8, 512, 0, stream>>>(h_b, wb2, B2, row_ptr,
                                                          s_meta, s_w, d_out, N);
}

// Round 9
// 441.081 us; speedup vs baseline: 10.3828x; 1.4244x over previous
//
#include <hip/hip_runtime.h>
#include <cstdint>

// SplineConv MeshEncoder: 3 layers, K=3 DIM=3 M=27, dims 3->64->64->64.
// R22 = R21 MFMA Phase A with the staging-order bug fixed:
//   R21 read w8fL in the A-frag build BEFORE the vmcnt(0) covering its
//   per-chunk staging (flagged in-round, shipped broken -> absmax 1.65).
//   Fix: w8f staged at WINDOW level (64 edges, 2KB, 2x gload_lds w16),
//   covered by the same vmcnt(0) as meta. Per chunk: issue 4 feature
//   gload_lds -> A-frag build from landed w8fL/metaL (overlaps feature
//   flight) -> vmcnt(0) -> B-frag ds_reads -> 8 MFMA.
//   Verified-against-proven-components: A-frag lane layout == Phase B's
//   passing accb/wb convention; C-write == m89 mapping (passing
//   epilogue); granule XOR swizzle algebra closes (G = e*8+(c3^(e>>3))
//   on both sides); digit identity re-derived.
//   R16 lesson: NO LDS atomics. R14: bf16 h. R20 lesson: no tr_read.

typedef __attribute__((ext_vector_type(8))) short short8;
typedef __attribute__((ext_vector_type(4))) float floatx4;

#define AS1 __attribute__((address_space(1)))
#define AS3 __attribute__((address_space(3)))

__device__ inline short f2bf(float f) {
    union { float f; unsigned u; } x; x.f = f;
    unsigned r = x.u + 0x7FFF + ((x.u >> 16) & 1);   // round-to-nearest-even
    return (short)(r >> 16);
}

__device__ inline float bf2f(unsigned short u) {
    union { unsigned u; float f; } x;
    x.u = ((unsigned)u) << 16;
    return x.f;
}

// ---------------- preprocessing (R10-proven) ----------------

__global__ void count_kernel(const int* __restrict__ ei, int* __restrict__ count, int E) {
    int e = blockIdx.x * blockDim.x + threadIdx.x;
    if (e < E) atomicAdd(&count[ei[E + e]], 1);
}

__global__ __launch_bounds__(1024) void scan_tile_kernel(const int* __restrict__ count,
                                                         int* __restrict__ row_ptr,
                                                         int* __restrict__ bsum, int N) {
    __shared__ int wsum[16];
    int tid = threadIdx.x, lane = tid & 63, wid = tid >> 6;
    int i = blockIdx.x * 1024 + tid;
    int v = (i < N) ? count[i] : 0;
    int incl = v;
#pragma unroll
    for (int off = 1; off < 64; off <<= 1) {
        int t = __shfl_up(incl, off, 64);
        if (lane >= off) incl += t;
    }
    if (lane == 63) wsum[wid] = incl;
    __syncthreads();
    if (tid < 16) {
        int w = wsum[tid];
#pragma unroll
        for (int off = 1; off < 16; off <<= 1) {
            int t = __shfl_up(w, off, 16);
            if ((tid & 15) >= off) w += t;
        }
        wsum[tid] = w;
    }
    __syncthreads();
    int waveoff = (wid > 0) ? wsum[wid - 1] : 0;
    if (i < N) row_ptr[i] = waveoff + incl - v;
    if (tid == 1023) bsum[blockIdx.x] = waveoff + incl;
}

__global__ __launch_bounds__(64) void scan_bsum_kernel(const int* __restrict__ bsum,
                                                       int* __restrict__ boff,
                                                       int* __restrict__ tot, int nb) {
    int tid = threadIdx.x;
    int v = (tid < nb) ? bsum[tid] : 0;
    int incl = v;
#pragma unroll
    for (int off = 1; off < 64; off <<= 1) {
        int t = __shfl_up(incl, off, 64);
        if (tid >= off) incl += t;
    }
    boff[tid] = incl - v;
    if (tid == 63) tot[0] = incl;
}

__global__ __launch_bounds__(1024) void scan_add_kernel(int* __restrict__ row_ptr,
                                                        const int* __restrict__ boff,
                                                        const int* __restrict__ tot,
                                                        int* __restrict__ cursor, int N) {
    int i = blockIdx.x * 1024 + threadIdx.x;
    if (i < N) {
        int r = row_ptr[i] + boff[blockIdx.x];
        row_ptr[i] = r;
        cursor[i] = r;
    }
    if (i == 0) row_ptr[N] = tot[0];
}

// meta = src | base<<24 | d0<<28 | d1<<29 | d2<<30 (base = d0+3d1+9d2).
// w f32 x8 per edge (pre-scaled by 1/deg), dst-sorted position.
__global__ void basis_sort_kernel(const int* __restrict__ ei, const float* __restrict__ attr,
                                  const int* __restrict__ count, int* __restrict__ cursor,
                                  int* __restrict__ s_meta, float* __restrict__ s_w, int E) {
    int e = blockIdx.x * blockDim.x + threadIdx.x;
    if (e >= E) return;
    int src = ei[e];
    int dst = ei[E + e];
    float f[3]; int i0[3];
#pragma unroll
    for (int d = 0; d < 3; d++) {
        float pos = attr[e * 3 + d] * 2.0f;          // K-1 = 2
        float fl = floorf(pos);
        fl = fminf(fmaxf(fl, 0.0f), 1.0f);           // clip to [0, K-2]
        i0[d] = (int)fl;
        f[d] = pos - fl;
    }
    int base = i0[0] + 3 * i0[1] + 9 * i0[2];        // in {0,1,3,4,9,10,12,13}
    float invd = 1.0f / fmaxf((float)count[dst], 1.0f);
    int p = atomicAdd(&cursor[dst], 1);
    s_meta[p] = src | (base << 24) | (i0[0] << 28) | (i0[1] << 29) | (i0[2] << 30);
    float w[8];
#pragma unroll
    for (int c = 0; c < 8; c++) {
        float ww = invd;
#pragma unroll
        for (int d = 0; d < 3; d++) {
            int off = (c >> d) & 1;
            ww *= off ? f[d] : (1.0f - f[d]);
        }
        w[c] = ww;
    }
    floatx4 w03 = {w[0], w[1], w[2], w[3]};
    floatx4 w47 = {w[4], w[5], w[6], w[7]};
    *(floatx4*)(s_w + (size_t)p * 8) = w03;
    *(floatx4*)(s_w + (size_t)p * 8 + 4) = w47;
}

// Pre-swizzle [W(1728,64); Wr(64,64)] into bf16 MFMA B-frag order (R1-proven).
__global__ void build_wb2(const float* __restrict__ Wa, const float* __restrict__ Ra,
                          unsigned short* __restrict__ wba,
                          const float* __restrict__ Wb, const float* __restrict__ Rb,
                          unsigned short* __restrict__ wbb) {
    int idx0 = blockIdx.x * blockDim.x + threadIdx.x;   // [0, 2*4*56*64)
    int half = idx0 / (4 * 56 * 64);
    if (half >= 2) return;
    int idx = idx0 - half * (4 * 56 * 64);
    const float* W = half ? Wb : Wa;
    const float* Wr = half ? Rb : Ra;
    unsigned short* wb = half ? wbb : wba;
    int l = idx & 63;
    int c = (idx >> 6) % 56;
    int t = idx / (56 * 64);
    int q = l >> 4, o = t * 16 + (l & 15);
    short8 out;
#pragma unroll
    for (int j = 0; j < 8; j++) {
        int k = c * 32 + q * 8 + j;
        float v = (k < 1728) ? W[(size_t)k * 64 + o] : Wr[(size_t)(k - 1728) * 64 + o];
        out[j] = f2bf(v);
    }
    *(short8*)(wb + (size_t)idx * 8) = out;
}

// ---------------- layer 0 (CIN=3): dual-edge Phase A (R19-identical) ----------------
__global__ __launch_bounds__(256) void layer0_kernel(
    const float* __restrict__ x, const float* __restrict__ W0,
    const float* __restrict__ Wr, const float* __restrict__ bias,
    const int* __restrict__ row_ptr, const int* __restrict__ s_meta,
    const float* __restrict__ s_w, unsigned short* __restrict__ h_out, int N) {
    constexpr int NPB = 32, KT = 84;
    __shared__ __align__(16) float acc[NPB * 2 * KT];   // 21.5 KB (dual copies)
    int tid = threadIdx.x, lane = tid & 63, wv = tid >> 6;
    int n0 = blockIdx.x * NPB;
    for (int k = tid; k < NPB * 2 * KT; k += 256) acc[k] = 0.0f;
    __syncthreads();

    int d = lane >> 5, hl = lane & 31;
    int c = hl / 3, i = hl - c * 3;
    bool act = (hl < 24);
    int cc = act ? c : 0;
    int coff = (c & 1) + 3 * ((c >> 1) & 1) + 9 * (c >> 2);   // corner offset

    for (int g2 = 0; g2 < 8; g2++) {
        int g = wv * 8 + g2;
        int n = n0 + g;
        if (n >= N) continue;
        if (lane < 3) acc[(g * 2) * KT + 81 + lane] = x[(size_t)n * 3 + lane];  // root
        int rs = row_ptr[n], re = row_ptr[n + 1];
        int npairs = (re - rs + 1) >> 1;
        float* accd = &acc[(g * 2 + d) * KT];
        for (int pb = 0; pb < npairs; pb += 4) {
            int metas[4]; float ws_[4], xs_[4];
#pragma unroll
            for (int j = 0; j < 4; j++) {            // clamp invalid -> rs (valid, w=0)
                int ej = rs + (pb + j) * 2 + d;
                bool v = (pb + j < npairs) && (ej < re);
                int ec = v ? ej : rs;
                metas[j] = s_meta[ec];
                float wv_ = s_w[(size_t)ec * 8 + cc];
                ws_[j] = v ? wv_ : 0.0f;
            }
#pragma unroll
            for (int j = 0; j < 4; j++)
                xs_[j] = x[(size_t)(metas[j] & 0xFFFFFF) * 3 + i];
#pragma unroll
            for (int j = 0; j < 4; j++) {
                int kidx = ((metas[j] >> 24) & 0xF) + coff;
                if (act) accd[kidx * 3 + i] += ws_[j] * xs_[j];
            }
        }
    }
    __syncthreads();

    // Phase B: o = lane, W in 84 registers; sum the dual acc copies.
    int o = lane;
    float wreg[KT];
#pragma unroll
    for (int k = 0; k < KT; k++)
        wreg[k] = (k < 81) ? W0[k * 64 + o] : Wr[(k - 81) * 64 + o];
    float bv = bias[o];
    for (int g = wv; g < NPB; g += 4) {
        int n = n0 + g;
        if (n >= N) break;
        float s = bv;
#pragma unroll
        for (int k4 = 0; k4 < KT; k4 += 4) {
            floatx4 a0 = *(const floatx4*)&acc[(g * 2) * KT + k4];
            floatx4 a1 = *(const floatx4*)&acc[(g * 2 + 1) * KT + k4];
            s += (a0.x + a1.x) * wreg[k4] + (a0.y + a1.y) * wreg[k4 + 1]
               + (a0.z + a1.z) * wreg[k4 + 2] + (a0.w + a1.w) * wreg[k4 + 3];
        }
        h_out[(size_t)n * 64 + o] = (unsigned short)f2bf(fmaxf(s, 0.0f));
    }
}

// ---------------- 64-ch layers: MFMA Phase A (v3, order-fixed) ----------------
// Per-wave LDS region RGS=3216 shorts (6432B; dword-stride 1608 % 32 = 8
// keeps Phase B A-reads at the R12-proven 2-way pattern):
//   [0..2047]    feat: 32 edges x 64 ch bf16, granule-swizzled
//                (granule G = e*8 + (c3 ^ (e>>3)), 8 elems/granule)
//   [2048..3071] w8f: 64 edges x 8 f32 corner weights (WINDOW level)
//   [3072..3199] meta: 64 ints
//   [0..1791]    acc row (written AFTER the edge loop; aliases feat)
template <bool OUTF32>
__global__ __launch_bounds__(512, 4) void layer64_kernel(
    const unsigned short* __restrict__ h_in, const unsigned short* __restrict__ wb,
    const float* __restrict__ bias, const int* __restrict__ row_ptr,
    const int* __restrict__ s_meta, const float* __restrict__ s_w,
    void* __restrict__ h_out, int N) {
    constexpr int NPB = 8;
    constexpr int RGS = 3216;
    __shared__ __align__(16) unsigned short lds[NPB * RGS];   // 51,456 B
    int tid = threadIdx.x, lane = tid & 63;
    int wvu = __builtin_amdgcn_readfirstlane(tid >> 6);   // uniform wave id 0..7
    int n0 = blockIdx.x * NPB;
    int srow = lane & 15, sgrp = lane >> 4;

    unsigned short* reg = &lds[(size_t)wvu * RGS];
    unsigned short* featL = reg;                 // 4096 B
    float* w8fL = (float*)(reg + 2048);          // 2048 B (64 edges x 8 f32)
    int* metaL = (int*)(reg + 3072);             // 256 B

    // ---- Phase A: acc(27x64) = Wbasis(27 x deg) X(deg x 64) via MFMA ----
    {
        int n = n0 + wvu;
        if (n >= N) {   // tail hygiene: zero the row so Phase B sees no stale LDS
            for (int k = lane; k < 1792; k += 64) reg[k] = 0;
        } else {
            // row digits for fragment rows (matrix rows srow and srow+16)
            int r0a = srow % 3, r1a = (srow / 3) % 3, r2a = srow / 9;
            int rb = srow + 16;
            int r0b = rb % 3, r1b = (rb / 3) % 3, r2b = rb / 9;
            bool rv1 = (srow < 11);              // matrix rows 27..31 invalid

            floatx4 facc[2][4];
#pragma unroll
            for (int mt = 0; mt < 2; mt++)
#pragma unroll
                for (int nt = 0; nt < 4; nt++)
                    facc[mt][nt] = (floatx4){0.0f, 0.0f, 0.0f, 0.0f};

            int rs = row_ptr[n], re = row_ptr[n + 1];
            int deg = re - rs;
            for (int wbo = 0; wbo < deg; wbo += 64) {
                // ---- stage window: meta (64x4B) + w8f (64 edges x 8 f32) ----
                __builtin_amdgcn_global_load_lds(
                    (const AS1 unsigned int*)(s_meta + rs + wbo + lane),
                    (AS3 unsigned int*)metaL, 4, 0, 0);
#pragma unroll
                for (int k = 0; k < 2; k++) {
                    // instr k: lane L -> edge k*32+(L>>1), half L&1 (16B)
                    const float* wsrc = s_w + (size_t)(rs + wbo) * 8
                                      + k * 256 + lane * 4;
                    __builtin_amdgcn_global_load_lds(
                        (const AS1 unsigned int*)wsrc,
                        (AS3 unsigned int*)(w8fL + k * 256), 16, 0, 0);
                }
                asm volatile("s_waitcnt vmcnt(0)" ::: "memory");   // meta+w8f landed
                int dw = deg - wbo;
                int vmax = (dw < 64 ? dw : 64) - 1;
                for (int ch2 = 0; ch2 < 2; ch2++) {
                    int cb = ch2 * 32;
                    if (cb >= dw) break;
                    // ---- stage 32 edges' features: 4 x w16, swizzled src ----
                    //   lane L, instr i: edge el = cb + i*8 + (L>>3),
                    //   granule c3 = (L&7)^i  (linear dest =>
                    //   granule G = e*8 + (c3 ^ (e>>3)))
#pragma unroll
                    for (int i = 0; i < 4; i++) {
                        int el = cb + i * 8 + (lane >> 3);
                        if (el > vmax) el = vmax;
                        int ms = metaL[el] & 0xFFFFFF;
                        int c3 = (lane & 7) ^ i;
                        const unsigned short* srcp = h_in + (size_t)ms * 64 + c3 * 8;
                        __builtin_amdgcn_global_load_lds(
                            (const AS1 unsigned int*)srcp,
                            (AS3 unsigned int*)(featL + i * 512), 16, 0, 0);
                    }
                    // ---- A-frags (digit identity) while features fly ----
                    //   w8fL/metaL landed at window vmcnt(0) above.
                    short8 af0, af1;
#pragma unroll
                    for (int j = 0; j < 8; j++) {
                        int ec = cb + 8 * sgrp + j;          // window-local k
                        bool ve = ec < dw;
                        int m = metaL[ec];
                        int d0 = (m >> 28) & 1, d1 = (m >> 29) & 1, d2 = (m >> 30) & 1;
                        {
                            int c0 = r0a - d0, c1 = r1a - d1, c2 = r2a - d2;
                            bool vc = (((c0 | c1 | c2) & ~1) == 0) && ve;
                            int ci = (c0 + (c1 << 1) + (c2 << 2)) & 7;
                            float wf = w8fL[ec * 8 + ci];
                            af0[j] = vc ? f2bf(wf) : (short)0;
                        }
                        {
                            int c0 = r0b - d0, c1 = r1b - d1, c2 = r2b - d2;
                            bool vc = rv1 && (((c0 | c1 | c2) & ~1) == 0) && ve;
                            int ci = (c0 + (c1 << 1) + (c2 << 2)) & 7;
                            float wf = w8fL[ec * 8 + ci];
                            af1[j] = vc ? f2bf(wf) : (short)0;
                        }
                    }
                    asm volatile("s_waitcnt vmcnt(0)" ::: "memory");   // feat landed
                    // ---- B-frags from swizzled feat + 8 MFMA ----
#pragma unroll
                    for (int nt = 0; nt < 4; nt++) {
                        short8 bn;
#pragma unroll
                        for (int jj = 0; jj < 8; jj++) {
                            int e = sgrp * 8 + jj;           // chunk-local
                            int g = e * 8 + (((nt * 2) + (srow >> 3)) ^ sgrp);
                            bn[jj] = (short)featL[g * 8 + (srow & 7)];
                        }
                        facc[0][nt] = __builtin_amdgcn_mfma_f32_16x16x32_bf16(
                            af0, bn, facc[0][nt], 0, 0, 0);
                        facc[1][nt] = __builtin_amdgcn_mfma_f32_16x16x32_bf16(
                            af1, bn, facc[1][nt], 0, 0, 0);
                    }
                }
            }
            // ---- C write (layout: col=srow+16nt, row=sgrp*4+r+16mt) ----
#pragma unroll
            for (int mt = 0; mt < 2; mt++)
#pragma unroll
                for (int nt = 0; nt < 4; nt++)
#pragma unroll
                    for (int r = 0; r < 4; r++) {
                        int mrow = mt * 16 + sgrp * 4 + r;
                        if (mrow < 27)
                            reg[mrow * 64 + nt * 16 + srow] =
                                (unsigned short)f2bf(facc[mt][nt][r]);
                    }
            reg[1728 + lane] = h_in[(size_t)n * 64 + lane];   // root row (bf16)
        }
    }
    __syncthreads();

    // ---- Phase B: all 8 waves, 2-way split-K (broadcast A reads) ----
    {
        int t = wvu & 3;
        int hf = wvu >> 2;
        const unsigned short* ap = lds + (size_t)(lane & 7) * RGS + ((lane >> 4) * 8);
        floatx4 fpb = {0.0f, 0.0f, 0.0f, 0.0f};
        const unsigned short* wbp = wb + ((size_t)(t * 56) * 64 + lane) * 8;
#pragma unroll
        for (int ci = 0; ci < 28; ci++) {
            int c = hf * 28 + ci;
            short8 af = *(const short8*)(ap + c * 32);
            short8 bfr = *(const short8*)(wbp + (size_t)c * 64 * 8);
            fpb = __builtin_amdgcn_mfma_f32_16x16x32_bf16(af, bfr, fpb, 0, 0, 0);
        }
        __syncthreads();               // all MFMA reads of lds complete
        float* pfw = (float*)(lds + (size_t)wvu * RGS);
#pragma unroll
        for (int r = 0; r < 4; r++) pfw[r * 64 + lane] = fpb[r];
        __syncthreads();
        if (wvu < 4) {
            int o = t * 16 + (lane & 15);
            float bv = bias[o];
            const float* pft = (const float*)(lds + (size_t)t * RGS);
            const float* pfu = (const float*)(lds + (size_t)(t + 4) * RGS);
#pragma unroll
            for (int r = 0; r < 4; r++) {
                int m = (lane >> 4) * 4 + r;
                if (m < 8) {
                    int n = n0 + m;
                    if (n < N) {
                        float s = pft[r * 64 + lane] + pfu[r * 64 + lane];
                        float val = fmaxf(s + bv, 0.0f);
                        if (OUTF32) {
                            ((float*)h_out)[(size_t)n * 64 + o] = val;
                        } else {
                            ((unsigned short*)h_out)[(size_t)n * 64 + o] =
                                (unsigned short)f2bf(val);
                        }
                    }
                }
            }
        }
    }
}

extern "C" void kernel_launch(void* const* d_in, const int* in_sizes, int n_in,
                              void* d_out, int out_size, void* d_ws, size_t ws_size,
                              hipStream_t stream) {
    (void)n_in; (void)out_size; (void)ws_size;
    const float* x    = (const float*)d_in[0];
    const int*   ei   = (const int*)d_in[1];
    const float* attr = (const float*)d_in[2];
    const float* W0 = (const float*)d_in[3];
    const float* R0 = (const float*)d_in[4];
    const float* B0 = (const float*)d_in[5];
    const float* W1 = (const float*)d_in[6];
    const float* R1 = (const float*)d_in[7];
    const float* B1 = (const float*)d_in[8];
    const float* W2 = (const float*)d_in[9];
    const float* R2 = (const float*)d_in[10];
    const float* B2 = (const float*)d_in[11];
    const int N = in_sizes[0] / 3;
    const int E = in_sizes[1] / 2;

    char* ws = (char*)d_ws;
    size_t off = 0;
    auto alloc = [&](size_t bytes) {
        size_t cur = off;
        off = (off + bytes + 255) & ~(size_t)255;
        return cur;
    };
    int* row_ptr = (int*)(ws + alloc((size_t)(N + 1) * 4));
    int* count   = (int*)(ws + alloc((size_t)N * 4));
    int* cursor  = (int*)(ws + alloc((size_t)N * 4));
    int* bsum    = (int*)(ws + alloc(64 * 4));
    int* boff    = (int*)(ws + alloc(64 * 4));
    int* tot     = (int*)(ws + alloc(4));
    int* s_meta  = (int*)(ws + alloc((size_t)E * 4));
    float* s_w   = (float*)(ws + alloc((size_t)E * 8 * 4));
    unsigned short* h_a = (unsigned short*)(ws + alloc((size_t)N * 64 * 2));
    unsigned short* h_b = (unsigned short*)(ws + alloc((size_t)N * 64 * 2));
    unsigned short* wb1 = (unsigned short*)(ws + alloc((size_t)4 * 56 * 64 * 8 * 2));
    unsigned short* wb2 = (unsigned short*)(ws + alloc((size_t)4 * 56 * 64 * 8 * 2));

    int nb = (N + 1023) / 1024;   // 49 <= 64

    hipMemsetAsync(count, 0, (size_t)N * 4, stream);
    count_kernel<<<(E + 255) / 256, 256, 0, stream>>>(ei, count, E);
    scan_tile_kernel<<<nb, 1024, 0, stream>>>(count, row_ptr, bsum, N);
    scan_bsum_kernel<<<1, 64, 0, stream>>>(bsum, boff, tot, nb);
    scan_add_kernel<<<nb, 1024, 0, stream>>>(row_ptr, boff, tot, cursor, N);
    basis_sort_kernel<<<(E + 255) / 256, 256, 0, stream>>>(ei, attr, count, cursor,
                                                           s_meta, s_w, E);
    build_wb2<<<(2 * 4 * 56 * 64 + 255) / 256, 256, 0, stream>>>(W1, R1, wb1,
                                                                 W2, R2, wb2);

    layer0_kernel<<<(N + 31) / 32, 256, 0, stream>>>(x, W0, R0, B0, row_ptr,
                                                     s_meta, s_w, h_a, N);
    layer64_kernel<false><<<(N + 7) / 8, 512, 0, stream>>>(h_a, wb1, B1, row_ptr,
                                                           s_meta, s_w, h_b, N);
    layer64_kernel<true><<<(N + 7) / 8, 512, 0, stream>>>(h_b, wb2, B2, row_ptr,
                                                          s_meta, s_w, d_out, N);
}

// Round 10
// 435.218 us; speedup vs baseline: 10.5227x; 1.0135x over previous
//
#include <hip/hip_runtime.h>
#include <cstdint>

// SplineConv MeshEncoder: 3 layers, K=3 DIM=3 M=27, dims 3->64->64->64.
// R23 = R22 (MFMA Phase A, PASSING, 441us) + three LDS-pressure cuts:
//   Diagnosis: layer64 @116us has VALUBusy 45%, MfmaUtil 10%, conflicts
//   6.1M -- no pipe saturated except LDS issue rate (tally: ~11k LDS
//   cycles/block x 24.4 blocks/CU ~= the whole dispatch). Cuts:
//   (1) Phase B 4-wave: waves 0-3 compute TWO 16-col groups per A-frag
//       read -> A ds_read_b128 224->112 per block.
//   (2) conflict-free B-frag swizzle: c3 = (lane&7)^(i<<1) at staging,
//       g = (2nt+b)^(sgrp<<1) at read -> 64 lanes hit 32 banks (2-way,
//       free) instead of 16 slots (4-way).
//   (3) counted vmcnt window pipeline: meta->w8->vmcnt(2)->feat issue->
//       vmcnt(4)->A-frag build->vmcnt(0)->MFMA (one drain saved/window).
//   R16 lesson: NO LDS atomics. R14: bf16 h. R20 lesson: no tr_read.

typedef __attribute__((ext_vector_type(8))) short short8;
typedef __attribute__((ext_vector_type(4))) float floatx4;

#define AS1 __attribute__((address_space(1)))
#define AS3 __attribute__((address_space(3)))

__device__ inline short f2bf(float f) {
    union { float f; unsigned u; } x; x.f = f;
    unsigned r = x.u + 0x7FFF + ((x.u >> 16) & 1);   // round-to-nearest-even
    return (short)(r >> 16);
}

__device__ inline float bf2f(unsigned short u) {
    union { unsigned u; float f; } x;
    x.u = ((unsigned)u) << 16;
    return x.f;
}

// ---------------- preprocessing (R10-proven) ----------------

__global__ void count_kernel(const int* __restrict__ ei, int* __restrict__ count, int E) {
    int e = blockIdx.x * blockDim.x + threadIdx.x;
    if (e < E) atomicAdd(&count[ei[E + e]], 1);
}

__global__ __launch_bounds__(1024) void scan_tile_kernel(const int* __restrict__ count,
                                                         int* __restrict__ row_ptr,
                                                         int* __restrict__ bsum, int N) {
    __shared__ int wsum[16];
    int tid = threadIdx.x, lane = tid & 63, wid = tid >> 6;
    int i = blockIdx.x * 1024 + tid;
    int v = (i < N) ? count[i] : 0;
    int incl = v;
#pragma unroll
    for (int off = 1; off < 64; off <<= 1) {
        int t = __shfl_up(incl, off, 64);
        if (lane >= off) incl += t;
    }
    if (lane == 63) wsum[wid] = incl;
    __syncthreads();
    if (tid < 16) {
        int w = wsum[tid];
#pragma unroll
        for (int off = 1; off < 16; off <<= 1) {
            int t = __shfl_up(w, off, 16);
            if ((tid & 15) >= off) w += t;
        }
        wsum[tid] = w;
    }
    __syncthreads();
    int waveoff = (wid > 0) ? wsum[wid - 1] : 0;
    if (i < N) row_ptr[i] = waveoff + incl - v;
    if (tid == 1023) bsum[blockIdx.x] = waveoff + incl;
}

__global__ __launch_bounds__(64) void scan_bsum_kernel(const int* __restrict__ bsum,
                                                       int* __restrict__ boff,
                                                       int* __restrict__ tot, int nb) {
    int tid = threadIdx.x;
    int v = (tid < nb) ? bsum[tid] : 0;
    int incl = v;
#pragma unroll
    for (int off = 1; off < 64; off <<= 1) {
        int t = __shfl_up(incl, off, 64);
        if (tid >= off) incl += t;
    }
    boff[tid] = incl - v;
    if (tid == 63) tot[0] = incl;
}

__global__ __launch_bounds__(1024) void scan_add_kernel(int* __restrict__ row_ptr,
                                                        const int* __restrict__ boff,
                                                        const int* __restrict__ tot,
                                                        int* __restrict__ cursor, int N) {
    int i = blockIdx.x * 1024 + threadIdx.x;
    if (i < N) {
        int r = row_ptr[i] + boff[blockIdx.x];
        row_ptr[i] = r;
        cursor[i] = r;
    }
    if (i == 0) row_ptr[N] = tot[0];
}

// meta = src | base<<24 | d0<<28 | d1<<29 | d2<<30 (base = d0+3d1+9d2).
// w f32 x8 per edge (pre-scaled by 1/deg), dst-sorted position.
__global__ void basis_sort_kernel(const int* __restrict__ ei, const float* __restrict__ attr,
                                  const int* __restrict__ count, int* __restrict__ cursor,
                                  int* __restrict__ s_meta, float* __restrict__ s_w, int E) {
    int e = blockIdx.x * blockDim.x + threadIdx.x;
    if (e >= E) return;
    int src = ei[e];
    int dst = ei[E + e];
    float f[3]; int i0[3];
#pragma unroll
    for (int d = 0; d < 3; d++) {
        float pos = attr[e * 3 + d] * 2.0f;          // K-1 = 2
        float fl = floorf(pos);
        fl = fminf(fmaxf(fl, 0.0f), 1.0f);           // clip to [0, K-2]
        i0[d] = (int)fl;
        f[d] = pos - fl;
    }
    int base = i0[0] + 3 * i0[1] + 9 * i0[2];        // in {0,1,3,4,9,10,12,13}
    float invd = 1.0f / fmaxf((float)count[dst], 1.0f);
    int p = atomicAdd(&cursor[dst], 1);
    s_meta[p] = src | (base << 24) | (i0[0] << 28) | (i0[1] << 29) | (i0[2] << 30);
    float w[8];
#pragma unroll
    for (int c = 0; c < 8; c++) {
        float ww = invd;
#pragma unroll
        for (int d = 0; d < 3; d++) {
            int off = (c >> d) & 1;
            ww *= off ? f[d] : (1.0f - f[d]);
        }
        w[c] = ww;
    }
    floatx4 w03 = {w[0], w[1], w[2], w[3]};
    floatx4 w47 = {w[4], w[5], w[6], w[7]};
    *(floatx4*)(s_w + (size_t)p * 8) = w03;
    *(floatx4*)(s_w + (size_t)p * 8 + 4) = w47;
}

// Pre-swizzle [W(1728,64); Wr(64,64)] into bf16 MFMA B-frag order (R1-proven).
__global__ void build_wb2(const float* __restrict__ Wa, const float* __restrict__ Ra,
                          unsigned short* __restrict__ wba,
                          const float* __restrict__ Wb, const float* __restrict__ Rb,
                          unsigned short* __restrict__ wbb) {
    int idx0 = blockIdx.x * blockDim.x + threadIdx.x;   // [0, 2*4*56*64)
    int half = idx0 / (4 * 56 * 64);
    if (half >= 2) return;
    int idx = idx0 - half * (4 * 56 * 64);
    const float* W = half ? Wb : Wa;
    const float* Wr = half ? Rb : Ra;
    unsigned short* wb = half ? wbb : wba;
    int l = idx & 63;
    int c = (idx >> 6) % 56;
    int t = idx / (56 * 64);
    int q = l >> 4, o = t * 16 + (l & 15);
    short8 out;
#pragma unroll
    for (int j = 0; j < 8; j++) {
        int k = c * 32 + q * 8 + j;
        float v = (k < 1728) ? W[(size_t)k * 64 + o] : Wr[(size_t)(k - 1728) * 64 + o];
        out[j] = f2bf(v);
    }
    *(short8*)(wb + (size_t)idx * 8) = out;
}

// ---------------- layer 0 (CIN=3): dual-edge Phase A (R19-identical) ----------------
__global__ __launch_bounds__(256) void layer0_kernel(
    const float* __restrict__ x, const float* __restrict__ W0,
    const float* __restrict__ Wr, const float* __restrict__ bias,
    const int* __restrict__ row_ptr, const int* __restrict__ s_meta,
    const float* __restrict__ s_w, unsigned short* __restrict__ h_out, int N) {
    constexpr int NPB = 32, KT = 84;
    __shared__ __align__(16) float acc[NPB * 2 * KT];   // 21.5 KB (dual copies)
    int tid = threadIdx.x, lane = tid & 63, wv = tid >> 6;
    int n0 = blockIdx.x * NPB;
    for (int k = tid; k < NPB * 2 * KT; k += 256) acc[k] = 0.0f;
    __syncthreads();

    int d = lane >> 5, hl = lane & 31;
    int c = hl / 3, i = hl - c * 3;
    bool act = (hl < 24);
    int cc = act ? c : 0;
    int coff = (c & 1) + 3 * ((c >> 1) & 1) + 9 * (c >> 2);   // corner offset

    for (int g2 = 0; g2 < 8; g2++) {
        int g = wv * 8 + g2;
        int n = n0 + g;
        if (n >= N) continue;
        if (lane < 3) acc[(g * 2) * KT + 81 + lane] = x[(size_t)n * 3 + lane];  // root
        int rs = row_ptr[n], re = row_ptr[n + 1];
        int npairs = (re - rs + 1) >> 1;
        float* accd = &acc[(g * 2 + d) * KT];
        for (int pb = 0; pb < npairs; pb += 4) {
            int metas[4]; float ws_[4], xs_[4];
#pragma unroll
            for (int j = 0; j < 4; j++) {            // clamp invalid -> rs (valid, w=0)
                int ej = rs + (pb + j) * 2 + d;
                bool v = (pb + j < npairs) && (ej < re);
                int ec = v ? ej : rs;
                metas[j] = s_meta[ec];
                float wv_ = s_w[(size_t)ec * 8 + cc];
                ws_[j] = v ? wv_ : 0.0f;
            }
#pragma unroll
            for (int j = 0; j < 4; j++)
                xs_[j] = x[(size_t)(metas[j] & 0xFFFFFF) * 3 + i];
#pragma unroll
            for (int j = 0; j < 4; j++) {
                int kidx = ((metas[j] >> 24) & 0xF) + coff;
                if (act) accd[kidx * 3 + i] += ws_[j] * xs_[j];
            }
        }
    }
    __syncthreads();

    // Phase B: o = lane, W in 84 registers; sum the dual acc copies.
    int o = lane;
    float wreg[KT];
#pragma unroll
    for (int k = 0; k < KT; k++)
        wreg[k] = (k < 81) ? W0[k * 64 + o] : Wr[(k - 81) * 64 + o];
    float bv = bias[o];
    for (int g = wv; g < NPB; g += 4) {
        int n = n0 + g;
        if (n >= N) break;
        float s = bv;
#pragma unroll
        for (int k4 = 0; k4 < KT; k4 += 4) {
            floatx4 a0 = *(const floatx4*)&acc[(g * 2) * KT + k4];
            floatx4 a1 = *(const floatx4*)&acc[(g * 2 + 1) * KT + k4];
            s += (a0.x + a1.x) * wreg[k4] + (a0.y + a1.y) * wreg[k4 + 1]
               + (a0.z + a1.z) * wreg[k4 + 2] + (a0.w + a1.w) * wreg[k4 + 3];
        }
        h_out[(size_t)n * 64 + o] = (unsigned short)f2bf(fmaxf(s, 0.0f));
    }
}

// ---------------- 64-ch layers: MFMA Phase A (v4) ----------------
// Per-wave LDS region RGS=3216 shorts (6432B; dword-stride 1608 % 32 = 8):
//   [0..2047]    feat: 32 edges x 64 ch bf16, granule-swizzled
//                (granule G = e*8 + (c3 ^ ((e>>3)<<1)), 8 elems/granule)
//   [2048..3071] w8f: 64 edges x 8 f32 corner weights (WINDOW level)
//   [3072..3199] meta: 64 ints
//   [0..1791]    acc row (written AFTER the edge loop; aliases feat)
template <bool OUTF32>
__global__ __launch_bounds__(512, 4) void layer64_kernel(
    const unsigned short* __restrict__ h_in, const unsigned short* __restrict__ wb,
    const float* __restrict__ bias, const int* __restrict__ row_ptr,
    const int* __restrict__ s_meta, const float* __restrict__ s_w,
    void* __restrict__ h_out, int N) {
    constexpr int NPB = 8;
    constexpr int RGS = 3216;
    __shared__ __align__(16) unsigned short lds[NPB * RGS];   // 51,456 B
    int tid = threadIdx.x, lane = tid & 63;
    int wvu = __builtin_amdgcn_readfirstlane(tid >> 6);   // uniform wave id 0..7
    int n0 = blockIdx.x * NPB;
    int srow = lane & 15, sgrp = lane >> 4;

    unsigned short* reg = &lds[(size_t)wvu * RGS];
    unsigned short* featL = reg;                 // 4096 B
    float* w8fL = (float*)(reg + 2048);          // 2048 B (64 edges x 8 f32)
    int* metaL = (int*)(reg + 3072);             // 256 B

    // ---- Phase A: acc(27x64) = Wbasis(27 x deg) X(deg x 64) via MFMA ----
    {
        int n = n0 + wvu;
        if (n >= N) {   // tail hygiene: zero the row so Phase B sees no stale LDS
            for (int k = lane; k < 1792; k += 64) reg[k] = 0;
        } else {
            // row digits for fragment rows (matrix rows srow and srow+16)
            int r0a = srow % 3, r1a = (srow / 3) % 3, r2a = srow / 9;
            int rb = srow + 16;
            int r0b = rb % 3, r1b = (rb / 3) % 3, r2b = rb / 9;
            bool rv1 = (srow < 11);              // matrix rows 27..31 invalid

            floatx4 facc[2][4];
#pragma unroll
            for (int mt = 0; mt < 2; mt++)
#pragma unroll
                for (int nt = 0; nt < 4; nt++)
                    facc[mt][nt] = (floatx4){0.0f, 0.0f, 0.0f, 0.0f};

            int rs = row_ptr[n], re = row_ptr[n + 1];
            int deg = re - rs;
            for (int wbo = 0; wbo < deg; wbo += 64) {
                // ---- issue window loads: meta FIRST, then w8 (2) ----
                __builtin_amdgcn_global_load_lds(
                    (const AS1 unsigned int*)(s_meta + rs + wbo + lane),
                    (AS3 unsigned int*)metaL, 4, 0, 0);
#pragma unroll
                for (int k = 0; k < 2; k++) {
                    const float* wsrc = s_w + (size_t)(rs + wbo) * 8
                                      + k * 256 + lane * 4;
                    __builtin_amdgcn_global_load_lds(
                        (const AS1 unsigned int*)wsrc,
                        (AS3 unsigned int*)(w8fL + k * 256), 16, 0, 0);
                }
                asm volatile("s_waitcnt vmcnt(2)" ::: "memory");   // meta landed
                int dw = deg - wbo;
                int vmax = (dw < 64 ? dw : 64) - 1;
                bool firstchunk = true;
                for (int ch2 = 0; ch2 < 2; ch2++) {
                    int cb = ch2 * 32;
                    if (cb >= dw) break;
                    // ---- stage 32 edges' features: 4 x w16, swizzled src ----
                    //   lane L, instr i: edge el = cb + i*8 + (L>>3),
                    //   granule c3 = (L&7) ^ (i<<1)  (linear dest =>
                    //   granule G = e*8 + (c3 ^ ((e>>3)<<1)))
#pragma unroll
                    for (int i = 0; i < 4; i++) {
                        int el = cb + i * 8 + (lane >> 3);
                        if (el > vmax) el = vmax;
                        int ms = metaL[el] & 0xFFFFFF;
                        int c3 = (lane & 7) ^ (i << 1);
                        const unsigned short* srcp = h_in + (size_t)ms * 64 + c3 * 8;
                        __builtin_amdgcn_global_load_lds(
                            (const AS1 unsigned int*)srcp,
                            (AS3 unsigned int*)(featL + i * 512), 16, 0, 0);
                    }
                    if (firstchunk) {   // retire the 2 w8 loads (oldest of 6)
                        asm volatile("s_waitcnt vmcnt(4)" ::: "memory");
                        firstchunk = false;
                    }
                    // ---- A-frags (digit identity); w8fL/metaL landed ----
                    short8 af0, af1;
#pragma unroll
                    for (int j = 0; j < 8; j++) {
                        int ec = cb + 8 * sgrp + j;          // window-local k
                        bool ve = ec < dw;
                        int m = metaL[ec];
                        int d0 = (m >> 28) & 1, d1 = (m >> 29) & 1, d2 = (m >> 30) & 1;
                        {
                            int c0 = r0a - d0, c1 = r1a - d1, c2 = r2a - d2;
                            bool vc = (((c0 | c1 | c2) & ~1) == 0) && ve;
                            int ci = (c0 + (c1 << 1) + (c2 << 2)) & 7;
                            float wf = w8fL[ec * 8 + ci];
                            af0[j] = vc ? f2bf(wf) : (short)0;
                        }
                        {
                            int c0 = r0b - d0, c1 = r1b - d1, c2 = r2b - d2;
                            bool vc = rv1 && (((c0 | c1 | c2) & ~1) == 0) && ve;
                            int ci = (c0 + (c1 << 1) + (c2 << 2)) & 7;
                            float wf = w8fL[ec * 8 + ci];
                            af1[j] = vc ? f2bf(wf) : (short)0;
                        }
                    }
                    asm volatile("s_waitcnt vmcnt(0)" ::: "memory");   // feat landed
                    // ---- B-frags from swizzled feat + 8 MFMA ----
#pragma unroll
                    for (int nt = 0; nt < 4; nt++) {
                        short8 bn;
#pragma unroll
                        for (int jj = 0; jj < 8; jj++) {
                            int e = sgrp * 8 + jj;           // chunk-local
                            int g = e * 8 + (((nt * 2) + (srow >> 3)) ^ (sgrp << 1));
                            bn[jj] = (short)featL[g * 8 + (srow & 7)];
                        }
                        facc[0][nt] = __builtin_amdgcn_mfma_f32_16x16x32_bf16(
                            af0, bn, facc[0][nt], 0, 0, 0);
                        facc[1][nt] = __builtin_amdgcn_mfma_f32_16x16x32_bf16(
                            af1, bn, facc[1][nt], 0, 0, 0);
                    }
                }
            }
            // ---- C write (layout: col=srow+16nt, row=sgrp*4+r+16mt) ----
#pragma unroll
            for (int mt = 0; mt < 2; mt++)
#pragma unroll
                for (int nt = 0; nt < 4; nt++)
#pragma unroll
                    for (int r = 0; r < 4; r++) {
                        int mrow = mt * 16 + sgrp * 4 + r;
                        if (mrow < 27)
                            reg[mrow * 64 + nt * 16 + srow] =
                                (unsigned short)f2bf(facc[mt][nt][r]);
                    }
            reg[1728 + lane] = h_in[(size_t)n * 64 + lane];   // root row (bf16)
        }
    }
    __syncthreads();

    // ---- Phase B: 4 waves, each 2 col-groups per A-read (LDS halved) ----
    {
        floatx4 f0 = {0.0f, 0.0f, 0.0f, 0.0f};
        floatx4 f1 = {0.0f, 0.0f, 0.0f, 0.0f};
        if (wvu < 4) {
            int hf = wvu >> 1;                   // K half: c in [hf*28, hf*28+28)
            int tp = wvu & 1;                    // col-group pair: nt = 2tp, 2tp+1
            const unsigned short* ap = lds + (size_t)(lane & 7) * RGS + ((lane >> 4) * 8);
            const unsigned short* wbp0 = wb + ((size_t)((tp * 2) * 56) * 64 + lane) * 8;
            const unsigned short* wbp1 = wb + ((size_t)((tp * 2 + 1) * 56) * 64 + lane) * 8;
#pragma unroll
            for (int ci = 0; ci < 28; ci++) {
                int c = hf * 28 + ci;
                short8 af = *(const short8*)(ap + c * 32);
                short8 b0 = *(const short8*)(wbp0 + (size_t)c * 64 * 8);
                short8 b1 = *(const short8*)(wbp1 + (size_t)c * 64 * 8);
                f0 = __builtin_amdgcn_mfma_f32_16x16x32_bf16(af, b0, f0, 0, 0, 0);
                f1 = __builtin_amdgcn_mfma_f32_16x16x32_bf16(af, b1, f1, 0, 0, 0);
            }
        }
        __syncthreads();               // all MFMA reads of lds complete
        if (wvu < 4) {
            float* pfw = (float*)(lds + (size_t)wvu * RGS);
#pragma unroll
            for (int r = 0; r < 4; r++) {
                pfw[r * 64 + lane] = f0[r];
                pfw[256 + r * 64 + lane] = f1[r];
            }
        }
        __syncthreads();
        if (wvu < 4) {
            int t = wvu;                         // output col group t
            int o = t * 16 + (lane & 15);
            float bv = bias[o];
            // producers: hf0 wave (t>>1), hf1 wave (2+(t>>1)); quad (t&1)
            const float* pfA = (const float*)(lds + (size_t)(t >> 1) * RGS)
                             + (t & 1) * 256;
            const float* pfB = (const float*)(lds + (size_t)(2 + (t >> 1)) * RGS)
                             + (t & 1) * 256;
#pragma unroll
            for (int r = 0; r < 4; r++) {
                int m = (lane >> 4) * 4 + r;
                if (m < 8) {
                    int n = n0 + m;
                    if (n < N) {
                        float s = pfA[r * 64 + lane] + pfB[r * 64 + lane];
                        float val = fmaxf(s + bv, 0.0f);
                        if (OUTF32) {
                            ((float*)h_out)[(size_t)n * 64 + o] = val;
                        } else {
                            ((unsigned short*)h_out)[(size_t)n * 64 + o] =
                                (unsigned short)f2bf(val);
                        }
                    }
                }
            }
        }
    }
}

extern "C" void kernel_launch(void* const* d_in, const int* in_sizes, int n_in,
                              void* d_out, int out_size, void* d_ws, size_t ws_size,
                              hipStream_t stream) {
    (void)n_in; (void)out_size; (void)ws_size;
    const float* x    = (const float*)d_in[0];
    const int*   ei   = (const int*)d_in[1];
    const float* attr = (const float*)d_in[2];
    const float* W0 = (const float*)d_in[3];
    const float* R0 = (const float*)d_in[4];
    const float* B0 = (const float*)d_in[5];
    const float* W1 = (const float*)d_in[6];
    const float* R1 = (const float*)d_in[7];
    const float* B1 = (const float*)d_in[8];
    const float* W2 = (const float*)d_in[9];
    const float* R2 = (const float*)d_in[10];
    const float* B2 = (const float*)d_in[11];
    const int N = in_sizes[0] / 3;
    const int E = in_sizes[1] / 2;

    char* ws = (char*)d_ws;
    size_t off = 0;
    auto alloc = [&](size_t bytes) {
        size_t cur = off;
        off = (off + bytes + 255) & ~(size_t)255;
        return cur;
    };
    int* row_ptr = (int*)(ws + alloc((size_t)(N + 1) * 4));
    int* count   = (int*)(ws + alloc((size_t)N * 4));
    int* cursor  = (int*)(ws + alloc((size_t)N * 4));
    int* bsum    = (int*)(ws + alloc(64 * 4));
    int* boff    = (int*)(ws + alloc(64 * 4));
    int* tot     = (int*)(ws + alloc(4));
    int* s_meta  = (int*)(ws + alloc((size_t)E * 4));
    float* s_w   = (float*)(ws + alloc((size_t)E * 8 * 4));
    unsigned short* h_a = (unsigned short*)(ws + alloc((size_t)N * 64 * 2));
    unsigned short* h_b = (unsigned short*)(ws + alloc((size_t)N * 64 * 2));
    unsigned short* wb1 = (unsigned short*)(ws + alloc((size_t)4 * 56 * 64 * 8 * 2));
    unsigned short* wb2 = (unsigned short*)(ws + alloc((size_t)4 * 56 * 64 * 8 * 2));

    int nb = (N + 1023) / 1024;   // 49 <= 64

    hipMemsetAsync(count, 0, (size_t)N * 4, stream);
    count_kernel<<<(E + 255) / 256, 256, 0, stream>>>(ei, count, E);
    scan_tile_kernel<<<nb, 1024, 0, stream>>>(count, row_ptr, bsum, N);
    scan_bsum_kernel<<<1, 64, 0, stream>>>(bsum, boff, tot, nb);
    scan_add_kernel<<<nb, 1024, 0, stream>>>(row_ptr, boff, tot, cursor, N);
    basis_sort_kernel<<<(E + 255) / 256, 256, 0, stream>>>(ei, attr, count, cursor,
                                                           s_meta, s_w, E);
    build_wb2<<<(2 * 4 * 56 * 64 + 255) / 256, 256, 0, stream>>>(W1, R1, wb1,
                                                                 W2, R2, wb2);

    layer0_kernel<<<(N + 31) / 32, 256, 0, stream>>>(x, W0, R0, B0, row_ptr,
                                                     s_meta, s_w, h_a, N);
    layer64_kernel<false><<<(N + 7) / 8, 512, 0, stream>>>(h_a, wb1, B1, row_ptr,
                                                           s_meta, s_w, h_b, N);
    layer64_kernel<true><<<(N + 7) / 8, 512, 0, stream>>>(h_b, wb2, B2, row_ptr,
                                                          s_meta, s_w, d_out, N);
}

// Round 12
// 430.900 us; speedup vs baseline: 10.6281x; 1.0100x over previous
//
#include <hip/hip_runtime.h>
#include <cstdint>

// SplineConv MeshEncoder: 3 layers, K=3 DIM=3 M=27, dims 3->64->64->64.
// R25 = R24 RESUBMITTED UNCHANGED (R11 bench was an infra failure:
// "MI355X container failed twice" -- kernel never ran).
// R24 = R23 (MFMA Phase A, 435us) + occupancy lift via LDS shrink:
//   Diagnosis: no pipe saturated (VALU 47%, LDS ~29%, MFMA 11%) yet
//   block time 10.8k cy >> VALU-bound 5.1k -> latency gaps; occupancy
//   40% (~1.6 blocks/CU), limited by 51.7KB LDS. Changes:
//   (1) bf16 s_w8 side array for layer64 (basis_sort writes both; s_w
//       f32 kept for layer0). ZERO numerics change (f2bf moved earlier,
//       same rounding). w8 staging 2 gloads -> 1; -16 f2bf/chunk.
//   (2) RGS 3216 -> 2704 shorts -> 43.3KB/block -> 3 blocks/CU.
//       (dword stride 1352 % 32 = 8: proven bank pattern preserved.)
//   (3) exact-count feature gloads (ngl = ceil(nsl/8)) + one-time feat
//       zero-init per wave (unstaged slots finite -> af=0 exact).
//   R16: NO LDS atomics. R14: bf16 h. R20: no tr_read.

typedef __attribute__((ext_vector_type(8))) short short8;
typedef __attribute__((ext_vector_type(4))) float floatx4;

#define AS1 __attribute__((address_space(1)))
#define AS3 __attribute__((address_space(3)))

__device__ inline short f2bf(float f) {
    union { float f; unsigned u; } x; x.f = f;
    unsigned r = x.u + 0x7FFF + ((x.u >> 16) & 1);   // round-to-nearest-even
    return (short)(r >> 16);
}

__device__ inline float bf2f(unsigned short u) {
    union { unsigned u; float f; } x;
    x.u = ((unsigned)u) << 16;
    return x.f;
}

// ---------------- preprocessing (R10-proven) ----------------

__global__ void count_kernel(const int* __restrict__ ei, int* __restrict__ count, int E) {
    int e = blockIdx.x * blockDim.x + threadIdx.x;
    if (e < E) atomicAdd(&count[ei[E + e]], 1);
}

__global__ __launch_bounds__(1024) void scan_tile_kernel(const int* __restrict__ count,
                                                         int* __restrict__ row_ptr,
                                                         int* __restrict__ bsum, int N) {
    __shared__ int wsum[16];
    int tid = threadIdx.x, lane = tid & 63, wid = tid >> 6;
    int i = blockIdx.x * 1024 + tid;
    int v = (i < N) ? count[i] : 0;
    int incl = v;
#pragma unroll
    for (int off = 1; off < 64; off <<= 1) {
        int t = __shfl_up(incl, off, 64);
        if (lane >= off) incl += t;
    }
    if (lane == 63) wsum[wid] = incl;
    __syncthreads();
    if (tid < 16) {
        int w = wsum[tid];
#pragma unroll
        for (int off = 1; off < 16; off <<= 1) {
            int t = __shfl_up(w, off, 16);
            if ((tid & 15) >= off) w += t;
        }
        wsum[tid] = w;
    }
    __syncthreads();
    int waveoff = (wid > 0) ? wsum[wid - 1] : 0;
    if (i < N) row_ptr[i] = waveoff + incl - v;
    if (tid == 1023) bsum[blockIdx.x] = waveoff + incl;
}

__global__ __launch_bounds__(64) void scan_bsum_kernel(const int* __restrict__ bsum,
                                                       int* __restrict__ boff,
                                                       int* __restrict__ tot, int nb) {
    int tid = threadIdx.x;
    int v = (tid < nb) ? bsum[tid] : 0;
    int incl = v;
#pragma unroll
    for (int off = 1; off < 64; off <<= 1) {
        int t = __shfl_up(incl, off, 64);
        if (tid >= off) incl += t;
    }
    boff[tid] = incl - v;
    if (tid == 63) tot[0] = incl;
}

__global__ __launch_bounds__(1024) void scan_add_kernel(int* __restrict__ row_ptr,
                                                        const int* __restrict__ boff,
                                                        const int* __restrict__ tot,
                                                        int* __restrict__ cursor, int N) {
    int i = blockIdx.x * 1024 + threadIdx.x;
    if (i < N) {
        int r = row_ptr[i] + boff[blockIdx.x];
        row_ptr[i] = r;
        cursor[i] = r;
    }
    if (i == 0) row_ptr[N] = tot[0];
}

// meta = src | base<<24 | d0<<28 | d1<<29 | d2<<30 (base = d0+3d1+9d2).
// s_w: f32 x8 (layer0); s_w8: bf16 x8 (layer64). Both dst-sorted.
__global__ void basis_sort_kernel(const int* __restrict__ ei, const float* __restrict__ attr,
                                  const int* __restrict__ count, int* __restrict__ cursor,
                                  int* __restrict__ s_meta, float* __restrict__ s_w,
                                  unsigned short* __restrict__ s_w8, int E) {
    int e = blockIdx.x * blockDim.x + threadIdx.x;
    if (e >= E) return;
    int src = ei[e];
    int dst = ei[E + e];
    float f[3]; int i0[3];
#pragma unroll
    for (int d = 0; d < 3; d++) {
        float pos = attr[e * 3 + d] * 2.0f;          // K-1 = 2
        float fl = floorf(pos);
        fl = fminf(fmaxf(fl, 0.0f), 1.0f);           // clip to [0, K-2]
        i0[d] = (int)fl;
        f[d] = pos - fl;
    }
    int base = i0[0] + 3 * i0[1] + 9 * i0[2];        // in {0,1,3,4,9,10,12,13}
    float invd = 1.0f / fmaxf((float)count[dst], 1.0f);
    int p = atomicAdd(&cursor[dst], 1);
    s_meta[p] = src | (base << 24) | (i0[0] << 28) | (i0[1] << 29) | (i0[2] << 30);
    float w[8];
    short8 pk8;
#pragma unroll
    for (int c = 0; c < 8; c++) {
        float ww = invd;
#pragma unroll
        for (int d = 0; d < 3; d++) {
            int off = (c >> d) & 1;
            ww *= off ? f[d] : (1.0f - f[d]);
        }
        w[c] = ww;
        pk8[c] = f2bf(ww);
    }
    floatx4 w03 = {w[0], w[1], w[2], w[3]};
    floatx4 w47 = {w[4], w[5], w[6], w[7]};
    *(floatx4*)(s_w + (size_t)p * 8) = w03;
    *(floatx4*)(s_w + (size_t)p * 8 + 4) = w47;
    *(short8*)(s_w8 + (size_t)p * 8) = pk8;
}

// Pre-swizzle [W(1728,64); Wr(64,64)] into bf16 MFMA B-frag order (R1-proven).
__global__ void build_wb2(const float* __restrict__ Wa, const float* __restrict__ Ra,
                          unsigned short* __restrict__ wba,
                          const float* __restrict__ Wb, const float* __restrict__ Rb,
                          unsigned short* __restrict__ wbb) {
    int idx0 = blockIdx.x * blockDim.x + threadIdx.x;   // [0, 2*4*56*64)
    int half = idx0 / (4 * 56 * 64);
    if (half >= 2) return;
    int idx = idx0 - half * (4 * 56 * 64);
    const float* W = half ? Wb : Wa;
    const float* Wr = half ? Rb : Ra;
    unsigned short* wb = half ? wbb : wba;
    int l = idx & 63;
    int c = (idx >> 6) % 56;
    int t = idx / (56 * 64);
    int q = l >> 4, o = t * 16 + (l & 15);
    short8 out;
#pragma unroll
    for (int j = 0; j < 8; j++) {
        int k = c * 32 + q * 8 + j;
        float v = (k < 1728) ? W[(size_t)k * 64 + o] : Wr[(size_t)(k - 1728) * 64 + o];
        out[j] = f2bf(v);
    }
    *(short8*)(wb + (size_t)idx * 8) = out;
}

// ---------------- layer 0 (CIN=3): dual-edge Phase A (unchanged, f32 w) ----------------
__global__ __launch_bounds__(256) void layer0_kernel(
    const float* __restrict__ x, const float* __restrict__ W0,
    const float* __restrict__ Wr, const float* __restrict__ bias,
    const int* __restrict__ row_ptr, const int* __restrict__ s_meta,
    const float* __restrict__ s_w, unsigned short* __restrict__ h_out, int N) {
    constexpr int NPB = 32, KT = 84;
    __shared__ __align__(16) float acc[NPB * 2 * KT];   // 21.5 KB (dual copies)
    int tid = threadIdx.x, lane = tid & 63, wv = tid >> 6;
    int n0 = blockIdx.x * NPB;
    for (int k = tid; k < NPB * 2 * KT; k += 256) acc[k] = 0.0f;
    __syncthreads();

    int d = lane >> 5, hl = lane & 31;
    int c = hl / 3, i = hl - c * 3;
    bool act = (hl < 24);
    int cc = act ? c : 0;
    int coff = (c & 1) + 3 * ((c >> 1) & 1) + 9 * (c >> 2);   // corner offset

    for (int g2 = 0; g2 < 8; g2++) {
        int g = wv * 8 + g2;
        int n = n0 + g;
        if (n >= N) continue;
        if (lane < 3) acc[(g * 2) * KT + 81 + lane] = x[(size_t)n * 3 + lane];  // root
        int rs = row_ptr[n], re = row_ptr[n + 1];
        int npairs = (re - rs + 1) >> 1;
        float* accd = &acc[(g * 2 + d) * KT];
        for (int pb = 0; pb < npairs; pb += 4) {
            int metas[4]; float ws_[4], xs_[4];
#pragma unroll
            for (int j = 0; j < 4; j++) {            // clamp invalid -> rs (valid, w=0)
                int ej = rs + (pb + j) * 2 + d;
                bool v = (pb + j < npairs) && (ej < re);
                int ec = v ? ej : rs;
                metas[j] = s_meta[ec];
                float wv_ = s_w[(size_t)ec * 8 + cc];
                ws_[j] = v ? wv_ : 0.0f;
            }
#pragma unroll
            for (int j = 0; j < 4; j++)
                xs_[j] = x[(size_t)(metas[j] & 0xFFFFFF) * 3 + i];
#pragma unroll
            for (int j = 0; j < 4; j++) {
                int kidx = ((metas[j] >> 24) & 0xF) + coff;
                if (act) accd[kidx * 3 + i] += ws_[j] * xs_[j];
            }
        }
    }
    __syncthreads();

    // Phase B: o = lane, W in 84 registers; sum the dual acc copies.
    int o = lane;
    float wreg[KT];
#pragma unroll
    for (int k = 0; k < KT; k++)
        wreg[k] = (k < 81) ? W0[k * 64 + o] : Wr[(k - 81) * 64 + o];
    float bv = bias[o];
    for (int g = wv; g < NPB; g += 4) {
        int n = n0 + g;
        if (n >= N) break;
        float s = bv;
#pragma unroll
        for (int k4 = 0; k4 < KT; k4 += 4) {
            floatx4 a0 = *(const floatx4*)&acc[(g * 2) * KT + k4];
            floatx4 a1 = *(const floatx4*)&acc[(g * 2 + 1) * KT + k4];
            s += (a0.x + a1.x) * wreg[k4] + (a0.y + a1.y) * wreg[k4 + 1]
               + (a0.z + a1.z) * wreg[k4 + 2] + (a0.w + a1.w) * wreg[k4 + 3];
        }
        h_out[(size_t)n * 64 + o] = (unsigned short)f2bf(fmaxf(s, 0.0f));
    }
}

// ---------------- 64-ch layers: MFMA Phase A (v5, slim LDS) ----------------
// Per-wave LDS region RGS=2704 shorts (5408B; dword-stride 1352 % 32 = 8):
//   [0..2047]    feat: 32 edges x 64 ch bf16, granule-swizzled
//                (granule G = e*8 + (c3 ^ ((e>>3)<<1)), 8 elems/granule)
//   [2048..2559] w8S: 64 edges x 8 bf16 corner weights (WINDOW level)
//   [2560..2687] meta: 64 ints
//   [0..1791]    acc row (written AFTER the edge loop; aliases feat)
template <bool OUTF32>
__global__ __launch_bounds__(512, 4) void layer64_kernel(
    const unsigned short* __restrict__ h_in, const unsigned short* __restrict__ wb,
    const float* __restrict__ bias, const int* __restrict__ row_ptr,
    const int* __restrict__ s_meta, const unsigned short* __restrict__ s_w8,
    void* __restrict__ h_out, int N) {
    constexpr int NPB = 8;
    constexpr int RGS = 2704;
    __shared__ __align__(16) unsigned short lds[NPB * RGS];   // 43,264 B
    int tid = threadIdx.x, lane = tid & 63;
    int wvu = __builtin_amdgcn_readfirstlane(tid >> 6);   // uniform wave id 0..7
    int n0 = blockIdx.x * NPB;
    int srow = lane & 15, sgrp = lane >> 4;

    unsigned short* reg = &lds[(size_t)wvu * RGS];
    unsigned short* featL = reg;                     // 4096 B
    unsigned short* w8SL = reg + 2048;               // 1024 B (64 edges x 8 bf16)
    int* metaL = (int*)(reg + 2560);                 // 256 B

    // ---- Phase A: acc(27x64) = Wbasis(27 x deg) X(deg x 64) via MFMA ----
    {
        int n = n0 + wvu;
        if (n >= N) {   // tail hygiene: zero the row so Phase B sees no stale LDS
            for (int k = lane; k < 1792; k += 64) reg[k] = 0;
        } else {
            // zero feat once: unstaged slots stay finite (af=0 covers them)
            {
                short8 z = {0, 0, 0, 0, 0, 0, 0, 0};
#pragma unroll
                for (int s = 0; s < 4; s++)
                    *(short8*)(featL + lane * 8 + s * 512) = z;
            }
            // row digits for fragment rows (matrix rows srow and srow+16)
            int r0a = srow % 3, r1a = (srow / 3) % 3, r2a = srow / 9;
            int rb = srow + 16;
            int r0b = rb % 3, r1b = (rb / 3) % 3, r2b = rb / 9;
            bool rv1 = (srow < 11);              // matrix rows 27..31 invalid

            floatx4 facc[2][4];
#pragma unroll
            for (int mt = 0; mt < 2; mt++)
#pragma unroll
                for (int nt = 0; nt < 4; nt++)
                    facc[mt][nt] = (floatx4){0.0f, 0.0f, 0.0f, 0.0f};

            int rs = row_ptr[n], re = row_ptr[n + 1];
            int deg = re - rs;
            for (int wbo = 0; wbo < deg; wbo += 64) {
                // ---- stage window: meta (64x4B) + w8 bf16 (64x16B, ONE instr) ----
                __builtin_amdgcn_global_load_lds(
                    (const AS1 unsigned int*)(s_meta + rs + wbo + lane),
                    (AS3 unsigned int*)metaL, 4, 0, 0);
                __builtin_amdgcn_global_load_lds(
                    (const AS1 unsigned int*)(s_w8 + (size_t)(rs + wbo + lane) * 8),
                    (AS3 unsigned int*)w8SL, 16, 0, 0);
                asm volatile("s_waitcnt vmcnt(0)" ::: "memory");   // meta+w8 landed
                int dw = deg - wbo;
                int vmax = (dw < 64 ? dw : 64) - 1;
                for (int ch2 = 0; ch2 < 2; ch2++) {
                    int cb = ch2 * 32;
                    if (cb >= dw) break;
                    // ---- stage features: exact-count w16 gloads, swizzled src ----
                    //   lane L, instr i: edge el = cb + i*8 + (L>>3),
                    //   granule c3 = (L&7) ^ (i<<1)  (linear dest =>
                    //   granule G = e*8 + (c3 ^ ((e>>3)<<1)))
                    int nsl = dw - cb; if (nsl > 32) nsl = 32;
                    int ngl = (nsl + 7) >> 3;
                    for (int i = 0; i < ngl; i++) {
                        int el = cb + i * 8 + (lane >> 3);
                        if (el > vmax) el = vmax;
                        int ms = metaL[el] & 0xFFFFFF;
                        int c3 = (lane & 7) ^ (i << 1);
                        const unsigned short* srcp = h_in + (size_t)ms * 64 + c3 * 8;
                        __builtin_amdgcn_global_load_lds(
                            (const AS1 unsigned int*)srcp,
                            (AS3 unsigned int*)(featL + i * 512), 16, 0, 0);
                    }
                    // ---- A-frags (digit identity) while features fly ----
                    short8 af0, af1;
#pragma unroll
                    for (int j = 0; j < 8; j++) {
                        int ec = cb + 8 * sgrp + j;          // window-local k
                        bool ve = ec < dw;
                        int m = metaL[ec];
                        int d0 = (m >> 28) & 1, d1 = (m >> 29) & 1, d2 = (m >> 30) & 1;
                        {
                            int c0 = r0a - d0, c1 = r1a - d1, c2 = r2a - d2;
                            bool vc = (((c0 | c1 | c2) & ~1) == 0) && ve;
                            int ci = (c0 + (c1 << 1) + (c2 << 2)) & 7;
                            unsigned short wv_ = w8SL[ec * 8 + ci];
                            af0[j] = vc ? (short)wv_ : (short)0;
                        }
                        {
                            int c0 = r0b - d0, c1 = r1b - d1, c2 = r2b - d2;
                            bool vc = rv1 && (((c0 | c1 | c2) & ~1) == 0) && ve;
                            int ci = (c0 + (c1 << 1) + (c2 << 2)) & 7;
                            unsigned short wv_ = w8SL[ec * 8 + ci];
                            af1[j] = vc ? (short)wv_ : (short)0;
                        }
                    }
                    asm volatile("s_waitcnt vmcnt(0)" ::: "memory");   // feat landed
                    // ---- B-frags from swizzled feat + 8 MFMA ----
#pragma unroll
                    for (int nt = 0; nt < 4; nt++) {
                        short8 bn;
#pragma unroll
                        for (int jj = 0; jj < 8; jj++) {
                            int e = sgrp * 8 + jj;           // chunk-local
                            int g = e * 8 + (((nt * 2) + (srow >> 3)) ^ (sgrp << 1));
                            bn[jj] = (short)featL[g * 8 + (srow & 7)];
                        }
                        facc[0][nt] = __builtin_amdgcn_mfma_f32_16x16x32_bf16(
                            af0, bn, facc[0][nt], 0, 0, 0);
                        facc[1][nt] = __builtin_amdgcn_mfma_f32_16x16x32_bf16(
                            af1, bn, facc[1][nt], 0, 0, 0);
                    }
                }
            }
            // ---- C write (layout: col=srow+16nt, row=sgrp*4+r+16mt) ----
#pragma unroll
            for (int mt = 0; mt < 2; mt++)
#pragma unroll
                for (int nt = 0; nt < 4; nt++)
#pragma unroll
                    for (int r = 0; r < 4; r++) {
                        int mrow = mt * 16 + sgrp * 4 + r;
                        if (mrow < 27)
                            reg[mrow * 64 + nt * 16 + srow] =
                                (unsigned short)f2bf(facc[mt][nt][r]);
                    }
            reg[1728 + lane] = h_in[(size_t)n * 64 + lane];   // root row (bf16)
        }
    }
    __syncthreads();

    // ---- Phase B: 4 waves, each 2 col-groups per A-read ----
    {
        floatx4 f0 = {0.0f, 0.0f, 0.0f, 0.0f};
        floatx4 f1 = {0.0f, 0.0f, 0.0f, 0.0f};
        if (wvu < 4) {
            int hf = wvu >> 1;                   // K half: c in [hf*28, hf*28+28)
            int tp = wvu & 1;                    // col-group pair: nt = 2tp, 2tp+1
            const unsigned short* ap = lds + (size_t)(lane & 7) * RGS + ((lane >> 4) * 8);
            const unsigned short* wbp0 = wb + ((size_t)((tp * 2) * 56) * 64 + lane) * 8;
            const unsigned short* wbp1 = wb + ((size_t)((tp * 2 + 1) * 56) * 64 + lane) * 8;
#pragma unroll
            for (int ci = 0; ci < 28; ci++) {
                int c = hf * 28 + ci;
                short8 af = *(const short8*)(ap + c * 32);
                short8 b0 = *(const short8*)(wbp0 + (size_t)c * 64 * 8);
                short8 b1 = *(const short8*)(wbp1 + (size_t)c * 64 * 8);
                f0 = __builtin_amdgcn_mfma_f32_16x16x32_bf16(af, b0, f0, 0, 0, 0);
                f1 = __builtin_amdgcn_mfma_f32_16x16x32_bf16(af, b1, f1, 0, 0, 0);
            }
        }
        __syncthreads();               // all MFMA reads of lds complete
        if (wvu < 4) {
            float* pfw = (float*)(lds + (size_t)wvu * RGS);
#pragma unroll
            for (int r = 0; r < 4; r++) {
                pfw[r * 64 + lane] = f0[r];
                pfw[256 + r * 64 + lane] = f1[r];
            }
        }
        __syncthreads();
        if (wvu < 4) {
            int t = wvu;                         // output col group t
            int o = t * 16 + (lane & 15);
            float bv = bias[o];
            // producers: hf0 wave (t>>1), hf1 wave (2+(t>>1)); quad (t&1)
            const float* pfA = (const float*)(lds + (size_t)(t >> 1) * RGS)
                             + (t & 1) * 256;
            const float* pfB = (const float*)(lds + (size_t)(2 + (t >> 1)) * RGS)
                             + (t & 1) * 256;
#pragma unroll
            for (int r = 0; r < 4; r++) {
                int m = (lane >> 4) * 4 + r;
                if (m < 8) {
                    int n = n0 + m;
                    if (n < N) {
                        float s = pfA[r * 64 + lane] + pfB[r * 64 + lane];
                        float val = fmaxf(s + bv, 0.0f);
                        if (OUTF32) {
                            ((float*)h_out)[(size_t)n * 64 + o] = val;
                        } else {
                            ((unsigned short*)h_out)[(size_t)n * 64 + o] =
                                (unsigned short)f2bf(val);
                        }
                    }
                }
            }
        }
    }
}

extern "C" void kernel_launch(void* const* d_in, const int* in_sizes, int n_in,
                              void* d_out, int out_size, void* d_ws, size_t ws_size,
                              hipStream_t stream) {
    (void)n_in; (void)out_size; (void)ws_size;
    const float* x    = (const float*)d_in[0];
    const int*   ei   = (const int*)d_in[1];
    const float* attr = (const float*)d_in[2];
    const float* W0 = (const float*)d_in[3];
    const float* R0 = (const float*)d_in[4];
    const float* B0 = (const float*)d_in[5];
    const float* W1 = (const float*)d_in[6];
    const float* R1 = (const float*)d_in[7];
    const float* B1 = (const float*)d_in[8];
    const float* W2 = (const float*)d_in[9];
    const float* R2 = (const float*)d_in[10];
    const float* B2 = (const float*)d_in[11];
    const int N = in_sizes[0] / 3;
    const int E = in_sizes[1] / 2;

    char* ws = (char*)d_ws;
    size_t off = 0;
    auto alloc = [&](size_t bytes) {
        size_t cur = off;
        off = (off + bytes + 255) & ~(size_t)255;
        return cur;
    };
    int* row_ptr = (int*)(ws + alloc((size_t)(N + 1) * 4));
    int* count   = (int*)(ws + alloc((size_t)N * 4));
    int* cursor  = (int*)(ws + alloc((size_t)N * 4));
    int* bsum    = (int*)(ws + alloc(64 * 4));
    int* boff    = (int*)(ws + alloc(64 * 4));
    int* tot     = (int*)(ws + alloc(4));
    int* s_meta  = (int*)(ws + alloc((size_t)E * 4));
    float* s_w   = (float*)(ws + alloc((size_t)E * 8 * 4));
    unsigned short* s_w8 = (unsigned short*)(ws + alloc((size_t)E * 8 * 2));
    unsigned short* h_a  = (unsigned short*)(ws + alloc((size_t)N * 64 * 2));
    unsigned short* h_b  = (unsigned short*)(ws + alloc((size_t)N * 64 * 2));
    unsigned short* wb1  = (unsigned short*)(ws + alloc((size_t)4 * 56 * 64 * 8 * 2));
    unsigned short* wb2  = (unsigned short*)(ws + alloc((size_t)4 * 56 * 64 * 8 * 2));

    int nb = (N + 1023) / 1024;   // 49 <= 64

    hipMemsetAsync(count, 0, (size_t)N * 4, stream);
    count_kernel<<<(E + 255) / 256, 256, 0, stream>>>(ei, count, E);
    scan_tile_kernel<<<nb, 1024, 0, stream>>>(count, row_ptr, bsum, N);
    scan_bsum_kernel<<<1, 64, 0, stream>>>(bsum, boff, tot, nb);
    scan_add_kernel<<<nb, 1024, 0, stream>>>(row_ptr, boff, tot, cursor, N);
    basis_sort_kernel<<<(E + 255) / 256, 256, 0, stream>>>(ei, attr, count, cursor,
                                                           s_meta, s_w, s_w8, E);
    build_wb2<<<(2 * 4 * 56 * 64 + 255) / 256, 256, 0, stream>>>(W1, R1, wb1,
                                                                 W2, R2, wb2);

    layer0_kernel<<<(N + 31) / 32, 256, 0, stream>>>(x, W0, R0, B0, row_ptr,
                                                     s_meta, s_w, h_a, N);
    layer64_kernel<false><<<(N + 7) / 8, 512, 0, stream>>>(h_a, wb1, B1, row_ptr,
                                                           s_meta, s_w8, h_b, N);
    layer64_kernel<true><<<(N + 7) / 8, 512, 0, stream>>>(h_b, wb2, B2, row_ptr,
                                                          s_meta, s_w8, d_out, N);
}

// Round 13
// 394.522 us; speedup vs baseline: 11.6081x; 1.0922x over previous
//
#include <hip/hip_runtime.h>
#include <cstdint>

// SplineConv MeshEncoder: 3 layers, K=3 DIM=3 M=27, dims 3->64->64->64.
// R26 = R25 (431us) + precomputed A-columns (s_wcol):
//   R25 verdict: occupancy lever DEAD (40% at both 51.7KB and 43.5KB LDS);
//   VALU tally still ~92 instrs/edge, dominated by the per-chunk A-frag
//   digit build (~208 VALU + 24 LDS per chunk). Fix: basis_sort scatters
//   each edge's 8 corner weights into a zeroed 32-entry bf16 column
//   s_wcol[e][32] (row = base + coff(c); rows 27-31 = 0). layer64 A-frag
//   build becomes 16 ds_read_u16 w/ immediate offsets -- no digits, no
//   validity (tail slots staged from zpad -> af=0; rows>=27 zero in data).
//   Rounding identical to R25 (f2bf(w_c) moved into basis_sort).
//   wcol staged per 32-edge chunk (2 gloads), single-buffered; reload for
//   chunk1 guarded by lgkmcnt(0)+sched_barrier (WAR vs A-build reads).
//   R16: NO LDS atomics. R14: bf16 h. R20: no tr_read.

typedef __attribute__((ext_vector_type(8))) short short8;
typedef __attribute__((ext_vector_type(4))) float floatx4;

#define AS1 __attribute__((address_space(1)))
#define AS3 __attribute__((address_space(3)))

__device__ inline short f2bf(float f) {
    union { float f; unsigned u; } x; x.f = f;
    unsigned r = x.u + 0x7FFF + ((x.u >> 16) & 1);   // round-to-nearest-even
    return (short)(r >> 16);
}

__device__ inline float bf2f(unsigned short u) {
    union { unsigned u; float f; } x;
    x.u = ((unsigned)u) << 16;
    return x.f;
}

// ---------------- preprocessing (R10-proven) ----------------

__global__ void count_kernel(const int* __restrict__ ei, int* __restrict__ count, int E) {
    int e = blockIdx.x * blockDim.x + threadIdx.x;
    if (e < E) atomicAdd(&count[ei[E + e]], 1);
}

__global__ __launch_bounds__(1024) void scan_tile_kernel(const int* __restrict__ count,
                                                         int* __restrict__ row_ptr,
                                                         int* __restrict__ bsum, int N) {
    __shared__ int wsum[16];
    int tid = threadIdx.x, lane = tid & 63, wid = tid >> 6;
    int i = blockIdx.x * 1024 + tid;
    int v = (i < N) ? count[i] : 0;
    int incl = v;
#pragma unroll
    for (int off = 1; off < 64; off <<= 1) {
        int t = __shfl_up(incl, off, 64);
        if (lane >= off) incl += t;
    }
    if (lane == 63) wsum[wid] = incl;
    __syncthreads();
    if (tid < 16) {
        int w = wsum[tid];
#pragma unroll
        for (int off = 1; off < 16; off <<= 1) {
            int t = __shfl_up(w, off, 16);
            if ((tid & 15) >= off) w += t;
        }
        wsum[tid] = w;
    }
    __syncthreads();
    int waveoff = (wid > 0) ? wsum[wid - 1] : 0;
    if (i < N) row_ptr[i] = waveoff + incl - v;
    if (tid == 1023) bsum[blockIdx.x] = waveoff + incl;
}

__global__ __launch_bounds__(64) void scan_bsum_kernel(const int* __restrict__ bsum,
                                                       int* __restrict__ boff,
                                                       int* __restrict__ tot, int nb) {
    int tid = threadIdx.x;
    int v = (tid < nb) ? bsum[tid] : 0;
    int incl = v;
#pragma unroll
    for (int off = 1; off < 64; off <<= 1) {
        int t = __shfl_up(incl, off, 64);
        if (tid >= off) incl += t;
    }
    boff[tid] = incl - v;
    if (tid == 63) tot[0] = incl;
}

__global__ __launch_bounds__(1024) void scan_add_kernel(int* __restrict__ row_ptr,
                                                        const int* __restrict__ boff,
                                                        const int* __restrict__ tot,
                                                        int* __restrict__ cursor, int N) {
    int i = blockIdx.x * 1024 + threadIdx.x;
    if (i < N) {
        int r = row_ptr[i] + boff[blockIdx.x];
        row_ptr[i] = r;
        cursor[i] = r;
    }
    if (i == 0) row_ptr[N] = tot[0];
}

// meta = src | base<<24 (bits 28-30 unused now). s_w: f32 x8 (layer0).
// s_wcol: 32 bf16 A-column per edge (row = base+coff(c); rows 27-31 = 0).
__global__ void basis_sort_kernel(const int* __restrict__ ei, const float* __restrict__ attr,
                                  const int* __restrict__ count, int* __restrict__ cursor,
                                  int* __restrict__ s_meta, float* __restrict__ s_w,
                                  unsigned short* __restrict__ s_wcol, int E) {
    int e = blockIdx.x * blockDim.x + threadIdx.x;
    if (e >= E) return;
    int src = ei[e];
    int dst = ei[E + e];
    float f[3]; int i0[3];
#pragma unroll
    for (int d = 0; d < 3; d++) {
        float pos = attr[e * 3 + d] * 2.0f;          // K-1 = 2
        float fl = floorf(pos);
        fl = fminf(fmaxf(fl, 0.0f), 1.0f);           // clip to [0, K-2]
        i0[d] = (int)fl;
        f[d] = pos - fl;
    }
    int base = i0[0] + 3 * i0[1] + 9 * i0[2];        // in {0,1,3,4,9,10,12,13}
    float invd = 1.0f / fmaxf((float)count[dst], 1.0f);
    int p = atomicAdd(&cursor[dst], 1);
    s_meta[p] = src | (base << 24);
    float w[8];
#pragma unroll
    for (int c = 0; c < 8; c++) {
        float ww = invd;
#pragma unroll
        for (int d = 0; d < 3; d++) {
            int off = (c >> d) & 1;
            ww *= off ? f[d] : (1.0f - f[d]);
        }
        w[c] = ww;
    }
    floatx4 w03 = {w[0], w[1], w[2], w[3]};
    floatx4 w47 = {w[4], w[5], w[6], w[7]};
    *(floatx4*)(s_w + (size_t)p * 8) = w03;
    *(floatx4*)(s_w + (size_t)p * 8 + 4) = w47;
    // A-column: zero 64B record, then scatter 8 bf16 (same line, prog order)
    unsigned short* wc = s_wcol + (size_t)p * 32;
    short8 z8 = {0, 0, 0, 0, 0, 0, 0, 0};
    *(short8*)(wc) = z8;
    *(short8*)(wc + 8) = z8;
    *(short8*)(wc + 16) = z8;
    *(short8*)(wc + 24) = z8;
#pragma unroll
    for (int c = 0; c < 8; c++) {
        int coff = (c & 1) + 3 * ((c >> 1) & 1) + 9 * (c >> 2);
        wc[base + coff] = (unsigned short)f2bf(w[c]);
    }
}

// Pre-swizzle [W(1728,64); Wr(64,64)] into bf16 MFMA B-frag order (R1-proven).
__global__ void build_wb2(const float* __restrict__ Wa, const float* __restrict__ Ra,
                          unsigned short* __restrict__ wba,
                          const float* __restrict__ Wb, const float* __restrict__ Rb,
                          unsigned short* __restrict__ wbb) {
    int idx0 = blockIdx.x * blockDim.x + threadIdx.x;   // [0, 2*4*56*64)
    int half = idx0 / (4 * 56 * 64);
    if (half >= 2) return;
    int idx = idx0 - half * (4 * 56 * 64);
    const float* W = half ? Wb : Wa;
    const float* Wr = half ? Rb : Ra;
    unsigned short* wb = half ? wbb : wba;
    int l = idx & 63;
    int c = (idx >> 6) % 56;
    int t = idx / (56 * 64);
    int q = l >> 4, o = t * 16 + (l & 15);
    short8 out;
#pragma unroll
    for (int j = 0; j < 8; j++) {
        int k = c * 32 + q * 8 + j;
        float v = (k < 1728) ? W[(size_t)k * 64 + o] : Wr[(size_t)(k - 1728) * 64 + o];
        out[j] = f2bf(v);
    }
    *(short8*)(wb + (size_t)idx * 8) = out;
}

// ---------------- layer 0 (CIN=3): dual-edge Phase A (unchanged, f32 w) ----------------
__global__ __launch_bounds__(256) void layer0_kernel(
    const float* __restrict__ x, const float* __restrict__ W0,
    const float* __restrict__ Wr, const float* __restrict__ bias,
    const int* __restrict__ row_ptr, const int* __restrict__ s_meta,
    const float* __restrict__ s_w, unsigned short* __restrict__ h_out, int N) {
    constexpr int NPB = 32, KT = 84;
    __shared__ __align__(16) float acc[NPB * 2 * KT];   // 21.5 KB (dual copies)
    int tid = threadIdx.x, lane = tid & 63, wv = tid >> 6;
    int n0 = blockIdx.x * NPB;
    for (int k = tid; k < NPB * 2 * KT; k += 256) acc[k] = 0.0f;
    __syncthreads();

    int d = lane >> 5, hl = lane & 31;
    int c = hl / 3, i = hl - c * 3;
    bool act = (hl < 24);
    int cc = act ? c : 0;
    int coff = (c & 1) + 3 * ((c >> 1) & 1) + 9 * (c >> 2);   // corner offset

    for (int g2 = 0; g2 < 8; g2++) {
        int g = wv * 8 + g2;
        int n = n0 + g;
        if (n >= N) continue;
        if (lane < 3) acc[(g * 2) * KT + 81 + lane] = x[(size_t)n * 3 + lane];  // root
        int rs = row_ptr[n], re = row_ptr[n + 1];
        int npairs = (re - rs + 1) >> 1;
        float* accd = &acc[(g * 2 + d) * KT];
        for (int pb = 0; pb < npairs; pb += 4) {
            int metas[4]; float ws_[4], xs_[4];
#pragma unroll
            for (int j = 0; j < 4; j++) {            // clamp invalid -> rs (valid, w=0)
                int ej = rs + (pb + j) * 2 + d;
                bool v = (pb + j < npairs) && (ej < re);
                int ec = v ? ej : rs;
                metas[j] = s_meta[ec];
                float wv_ = s_w[(size_t)ec * 8 + cc];
                ws_[j] = v ? wv_ : 0.0f;
            }
#pragma unroll
            for (int j = 0; j < 4; j++)
                xs_[j] = x[(size_t)(metas[j] & 0xFFFFFF) * 3 + i];
#pragma unroll
            for (int j = 0; j < 4; j++) {
                int kidx = ((metas[j] >> 24) & 0xF) + coff;
                if (act) accd[kidx * 3 + i] += ws_[j] * xs_[j];
            }
        }
    }
    __syncthreads();

    // Phase B: o = lane, W in 84 registers; sum the dual acc copies.
    int o = lane;
    float wreg[KT];
#pragma unroll
    for (int k = 0; k < KT; k++)
        wreg[k] = (k < 81) ? W0[k * 64 + o] : Wr[(k - 81) * 64 + o];
    float bv = bias[o];
    for (int g = wv; g < NPB; g += 4) {
        int n = n0 + g;
        if (n >= N) break;
        float s = bv;
#pragma unroll
        for (int k4 = 0; k4 < KT; k4 += 4) {
            floatx4 a0 = *(const floatx4*)&acc[(g * 2) * KT + k4];
            floatx4 a1 = *(const floatx4*)&acc[(g * 2 + 1) * KT + k4];
            s += (a0.x + a1.x) * wreg[k4] + (a0.y + a1.y) * wreg[k4 + 1]
               + (a0.z + a1.z) * wreg[k4 + 2] + (a0.w + a1.w) * wreg[k4 + 3];
        }
        h_out[(size_t)n * 64 + o] = (unsigned short)f2bf(fmaxf(s, 0.0f));
    }
}

// ---------------- 64-ch layers: MFMA Phase A (v6, wcol A-columns) ----------------
// Per-wave LDS region RGS=3216 shorts (6432B; dword-stride 1608 % 32 = 8):
//   [0..2047]    feat: 32 edges x 64 ch bf16, granule-swizzled
//                (granule G = e*8 + (c3 ^ ((e>>3)<<1)), 8 elems/granule)
//   [2048..3071] wcol: 32 edges x 32 bf16 A-columns (CHUNK level)
//   [3072..3199] meta: 64 ints
//   [0..1791]    acc row (written AFTER the edge loop; aliases feat)
template <bool OUTF32>
__global__ __launch_bounds__(512, 4) void layer64_kernel(
    const unsigned short* __restrict__ h_in, const unsigned short* __restrict__ wb,
    const float* __restrict__ bias, const int* __restrict__ row_ptr,
    const int* __restrict__ s_meta, const unsigned short* __restrict__ s_wcol,
    const unsigned short* __restrict__ zpad, void* __restrict__ h_out, int N) {
    constexpr int NPB = 8;
    constexpr int RGS = 3216;
    __shared__ __align__(16) unsigned short lds[NPB * RGS];   // 51,456 B
    int tid = threadIdx.x, lane = tid & 63;
    int wvu = __builtin_amdgcn_readfirstlane(tid >> 6);   // uniform wave id 0..7
    int n0 = blockIdx.x * NPB;
    int srow = lane & 15, sgrp = lane >> 4;

    unsigned short* reg = &lds[(size_t)wvu * RGS];
    unsigned short* featL = reg;                     // 4096 B
    unsigned short* wcolL = reg + 2048;              // 2048 B (32 edges x 32 bf16)
    int* metaL = (int*)(reg + 3072);                 // 256 B

// stage wcol for 32 window-local edges starting at CB (clamped -> zpad)
#define STAGE_WCOL(CB) do { \
    _Pragma("unroll") for (int k = 0; k < 2; k++) { \
        int el = (CB) + k * 16 + (lane >> 2); \
        const unsigned short* srcp = (el < dw) \
            ? s_wcol + (size_t)(rs + wbo + el) * 32 + (lane & 3) * 8 \
            : zpad + (lane & 3) * 8; \
        __builtin_amdgcn_global_load_lds((const AS1 unsigned int*)srcp, \
            (AS3 unsigned int*)(wcolL + k * 512), 16, 0, 0); \
    } \
} while (0)

    // ---- Phase A: acc(27x64) = Wbasis(27 x deg) X(deg x 64) via MFMA ----
    {
        int n = n0 + wvu;
        if (n >= N) {   // tail hygiene: zero the row so Phase B sees no stale LDS
            for (int k = lane; k < 1792; k += 64) reg[k] = 0;
        } else {
            // zero feat once: unstaged slots stay finite (af=0 covers them)
            {
                short8 z = {0, 0, 0, 0, 0, 0, 0, 0};
#pragma unroll
                for (int s = 0; s < 4; s++)
                    *(short8*)(featL + lane * 8 + s * 512) = z;
            }
            floatx4 facc[2][4];
#pragma unroll
            for (int mt = 0; mt < 2; mt++)
#pragma unroll
                for (int nt = 0; nt < 4; nt++)
                    facc[mt][nt] = (floatx4){0.0f, 0.0f, 0.0f, 0.0f};

            int rs = row_ptr[n], re = row_ptr[n + 1];
            int deg = re - rs;
            for (int wbo = 0; wbo < deg; wbo += 64) {
                int dw = deg - wbo;
                // ---- stage window: meta (64x4B) + wcol chunk0 ----
                __builtin_amdgcn_global_load_lds(
                    (const AS1 unsigned int*)(s_meta + rs + wbo + lane),
                    (AS3 unsigned int*)metaL, 4, 0, 0);
                STAGE_WCOL(0);
                asm volatile("s_waitcnt vmcnt(0)" ::: "memory");   // meta+wcol0 landed
                int vmax = (dw < 64 ? dw : 64) - 1;
                for (int ch2 = 0; ch2 < 2; ch2++) {
                    int cb = ch2 * 32;
                    if (cb >= dw) break;
                    // ---- stage features: exact-count w16 gloads, swizzled src ----
                    //   lane L, instr i: edge el = cb + i*8 + (L>>3),
                    //   granule c3 = (L&7) ^ (i<<1)  (linear dest =>
                    //   granule G = e*8 + (c3 ^ ((e>>3)<<1)))
                    int nsl = dw - cb; if (nsl > 32) nsl = 32;
                    int ngl = (nsl + 7) >> 3;
                    for (int i = 0; i < ngl; i++) {
                        int el = cb + i * 8 + (lane >> 3);
                        if (el > vmax) el = vmax;
                        int ms = metaL[el] & 0xFFFFFF;
                        int c3 = (lane & 7) ^ (i << 1);
                        const unsigned short* srcp = h_in + (size_t)ms * 64 + c3 * 8;
                        __builtin_amdgcn_global_load_lds(
                            (const AS1 unsigned int*)srcp,
                            (AS3 unsigned int*)(featL + i * 512), 16, 0, 0);
                    }
                    // ---- A-frags: 16 ds_read_u16 from wcolL (imm offsets) ----
                    short8 af0, af1;
                    {
                        const unsigned short* wrp = wcolL + (8 * sgrp) * 32 + srow;
#pragma unroll
                        for (int j = 0; j < 8; j++) {
                            af0[j] = (short)wrp[j * 32];
                            af1[j] = (short)wrp[j * 32 + 16];
                        }
                    }
                    // chunk1's wcol reload (single-buffered): only after the
                    // A-build ds_reads completed (WAR guard).
                    if (ch2 == 0 && dw > 32) {
                        asm volatile("s_waitcnt lgkmcnt(0)" ::: "memory");
                        __builtin_amdgcn_sched_barrier(0);
                        STAGE_WCOL(32);
                    }
                    asm volatile("s_waitcnt vmcnt(0)" ::: "memory");   // feat landed
                    // ---- B-frags from swizzled feat + 8 MFMA ----
#pragma unroll
                    for (int nt = 0; nt < 4; nt++) {
                        short8 bn;
#pragma unroll
                        for (int jj = 0; jj < 8; jj++) {
                            int e = sgrp * 8 + jj;           // chunk-local
                            int g = e * 8 + (((nt * 2) + (srow >> 3)) ^ (sgrp << 1));
                            bn[jj] = (short)featL[g * 8 + (srow & 7)];
                        }
                        facc[0][nt] = __builtin_amdgcn_mfma_f32_16x16x32_bf16(
                            af0, bn, facc[0][nt], 0, 0, 0);
                        facc[1][nt] = __builtin_amdgcn_mfma_f32_16x16x32_bf16(
                            af1, bn, facc[1][nt], 0, 0, 0);
                    }
                }
            }
            // ---- C write (layout: col=srow+16nt, row=sgrp*4+r+16mt) ----
#pragma unroll
            for (int mt = 0; mt < 2; mt++)
#pragma unroll
                for (int nt = 0; nt < 4; nt++)
#pragma unroll
                    for (int r = 0; r < 4; r++) {
                        int mrow = mt * 16 + sgrp * 4 + r;
                        if (mrow < 27)
                            reg[mrow * 64 + nt * 16 + srow] =
                                (unsigned short)f2bf(facc[mt][nt][r]);
                    }
            reg[1728 + lane] = h_in[(size_t)n * 64 + lane];   // root row (bf16)
        }
    }
#undef STAGE_WCOL
    __syncthreads();

    // ---- Phase B: 4 waves, each 2 col-groups per A-read ----
    {
        floatx4 f0 = {0.0f, 0.0f, 0.0f, 0.0f};
        floatx4 f1 = {0.0f, 0.0f, 0.0f, 0.0f};
        if (wvu < 4) {
            int hf = wvu >> 1;                   // K half: c in [hf*28, hf*28+28)
            int tp = wvu & 1;                    // col-group pair: nt = 2tp, 2tp+1
            const unsigned short* ap = lds + (size_t)(lane & 7) * RGS + ((lane >> 4) * 8);
            const unsigned short* wbp0 = wb + ((size_t)((tp * 2) * 56) * 64 + lane) * 8;
            const unsigned short* wbp1 = wb + ((size_t)((tp * 2 + 1) * 56) * 64 + lane) * 8;
#pragma unroll
            for (int ci = 0; ci < 28; ci++) {
                int c = hf * 28 + ci;
                short8 af = *(const short8*)(ap + c * 32);
                short8 b0 = *(const short8*)(wbp0 + (size_t)c * 64 * 8);
                short8 b1 = *(const short8*)(wbp1 + (size_t)c * 64 * 8);
                f0 = __builtin_amdgcn_mfma_f32_16x16x32_bf16(af, b0, f0, 0, 0, 0);
                f1 = __builtin_amdgcn_mfma_f32_16x16x32_bf16(af, b1, f1, 0, 0, 0);
            }
        }
        __syncthreads();               // all MFMA reads of lds complete
        if (wvu < 4) {
            float* pfw = (float*)(lds + (size_t)wvu * RGS);
#pragma unroll
            for (int r = 0; r < 4; r++) {
                pfw[r * 64 + lane] = f0[r];
                pfw[256 + r * 64 + lane] = f1[r];
            }
        }
        __syncthreads();
        if (wvu < 4) {
            int t = wvu;                         // output col group t
            int o = t * 16 + (lane & 15);
            float bv = bias[o];
            // producers: hf0 wave (t>>1), hf1 wave (2+(t>>1)); quad (t&1)
            const float* pfA = (const float*)(lds + (size_t)(t >> 1) * RGS)
                             + (t & 1) * 256;
            const float* pfB = (const float*)(lds + (size_t)(2 + (t >> 1)) * RGS)
                             + (t & 1) * 256;
#pragma unroll
            for (int r = 0; r < 4; r++) {
                int m = (lane >> 4) * 4 + r;
                if (m < 8) {
                    int n = n0 + m;
                    if (n < N) {
                        float s = pfA[r * 64 + lane] + pfB[r * 64 + lane];
                        float val = fmaxf(s + bv, 0.0f);
                        if (OUTF32) {
                            ((float*)h_out)[(size_t)n * 64 + o] = val;
                        } else {
                            ((unsigned short*)h_out)[(size_t)n * 64 + o] =
                                (unsigned short)f2bf(val);
                        }
                    }
                }
            }
        }
    }
}

extern "C" void kernel_launch(void* const* d_in, const int* in_sizes, int n_in,
                              void* d_out, int out_size, void* d_ws, size_t ws_size,
                              hipStream_t stream) {
    (void)n_in; (void)out_size; (void)ws_size;
    const float* x    = (const float*)d_in[0];
    const int*   ei   = (const int*)d_in[1];
    const float* attr = (const float*)d_in[2];
    const float* W0 = (const float*)d_in[3];
    const float* R0 = (const float*)d_in[4];
    const float* B0 = (const float*)d_in[5];
    const float* W1 = (const float*)d_in[6];
    const float* R1 = (const float*)d_in[7];
    const float* B1 = (const float*)d_in[8];
    const float* W2 = (const float*)d_in[9];
    const float* R2 = (const float*)d_in[10];
    const float* B2 = (const float*)d_in[11];
    const int N = in_sizes[0] / 3;
    const int E = in_sizes[1] / 2;

    char* ws = (char*)d_ws;
    size_t off = 0;
    auto alloc = [&](size_t bytes) {
        size_t cur = off;
        off = (off + bytes + 255) & ~(size_t)255;
        return cur;
    };
    int* row_ptr = (int*)(ws + alloc((size_t)(N + 1) * 4));
    int* count   = (int*)(ws + alloc((size_t)N * 4));
    int* cursor  = (int*)(ws + alloc((size_t)N * 4));
    int* bsum    = (int*)(ws + alloc(64 * 4));
    int* boff    = (int*)(ws + alloc(64 * 4));
    int* tot     = (int*)(ws + alloc(4));
    unsigned short* zpad = (unsigned short*)(ws + alloc(256));
    int* s_meta  = (int*)(ws + alloc((size_t)E * 4));
    float* s_w   = (float*)(ws + alloc((size_t)E * 8 * 4));
    unsigned short* s_wcol = (unsigned short*)(ws + alloc((size_t)E * 32 * 2));
    unsigned short* h_a  = (unsigned short*)(ws + alloc((size_t)N * 64 * 2));
    unsigned short* h_b  = (unsigned short*)(ws + alloc((size_t)N * 64 * 2));
    unsigned short* wb1  = (unsigned short*)(ws + alloc((size_t)4 * 56 * 64 * 8 * 2));
    unsigned short* wb2  = (unsigned short*)(ws + alloc((size_t)4 * 56 * 64 * 8 * 2));

    int nb = (N + 1023) / 1024;   // 49 <= 64

    hipMemsetAsync(count, 0, (size_t)N * 4, stream);
    hipMemsetAsync(zpad, 0, 256, stream);
    count_kernel<<<(E + 255) / 256, 256, 0, stream>>>(ei, count, E);
    scan_tile_kernel<<<nb, 1024, 0, stream>>>(count, row_ptr, bsum, N);
    scan_bsum_kernel<<<1, 64, 0, stream>>>(bsum, boff, tot, nb);
    scan_add_kernel<<<nb, 1024, 0, stream>>>(row_ptr, boff, tot, cursor, N);
    basis_sort_kernel<<<(E + 255) / 256, 256, 0, stream>>>(ei, attr, count, cursor,
                                                           s_meta, s_w, s_wcol, E);
    build_wb2<<<(2 * 4 * 56 * 64 + 255) / 256, 256, 0, stream>>>(W1, R1, wb1,
                                                                 W2, R2, wb2);

    layer0_kernel<<<(N + 31) / 32, 256, 0, stream>>>(x, W0, R0, B0, row_ptr,
                                                     s_meta, s_w, h_a, N);
    layer64_kernel<false><<<(N + 7) / 8, 512, 0, stream>>>(h_a, wb1, B1, row_ptr,
                                                           s_meta, s_wcol, zpad, h_b, N);
    layer64_kernel<true><<<(N + 7) / 8, 512, 0, stream>>>(h_b, wb2, B2, row_ptr,
                                                          s_meta, s_wcol, zpad, d_out, N);
}